// Round 7
// baseline (509.306 us; speedup 1.0000x reference)
//
#include <hip/hip_runtime.h>

#define N_NODES  50000
#define N_EDGES  600000
#define DIM      128
#define N_LAYERS 5
#define N_GRAPHS 512
#define NB       ((N_NODES + 255) / 256)   // 196
#define NRANGE   16
#define RSPAN    3125                      // 16 * 3125 = 50000
#define NCHUNK   16
#define ESPAN    37500                     // 16 * 37500 = 600000

// bf16 <-> f32 bit helpers (RNE)
__device__ __forceinline__ unsigned short f2b(float f) {
    unsigned u = __float_as_uint(f);
    return (unsigned short)((u + 0x7FFFu + ((u >> 16) & 1u)) >> 16);
}
__device__ __forceinline__ float4 b2f4(ushort4 u) {
    float4 c;
    c.x = __uint_as_float((unsigned)u.x << 16);
    c.y = __uint_as_float((unsigned)u.y << 16);
    c.z = __uint_as_float((unsigned)u.z << 16);
    c.w = __uint_as_float((unsigned)u.w << 16);
    return c;
}

// ---------------------------------------------------------------- preprocess
// CSR build with ZERO global atomics: 16 node-ranges x 16 edge-chunks.

// partial[c][r][i] = #edges in chunk c with dst == r*RSPAN+i  (LDS histogram)
__global__ __launch_bounds__(256) void k_hist(const int* __restrict__ dst,
                                              int* __restrict__ partial,
                                              unsigned* __restrict__ gstart,
                                              unsigned* __restrict__ gend) {
    __shared__ int histo[RSPAN];
    const int r  = blockIdx.x & 15;
    const int c  = blockIdx.x >> 4;
    const int lo = r * RSPAN;
    for (int i = threadIdx.x; i < RSPAN; i += 256) histo[i] = 0;
    if (blockIdx.x == 0) {
        for (int i = threadIdx.x; i < N_GRAPHS; i += 256) { gstart[i] = 0u; gend[i] = 0u; }
    }
    __syncthreads();
    const int e0 = c * ESPAN;
    for (int e = e0 + threadIdx.x; e < e0 + ESPAN; e += 256) {
        int d = dst[e] - lo;
        if ((unsigned)d < (unsigned)RSPAN) atomicAdd(&histo[d], 1);
    }
    __syncthreads();
    int* p = partial + (size_t)(c * NRANGE + r) * RSPAN;
    for (int i = threadIdx.x; i < RSPAN; i += 256) p[i] = histo[i];
}

// per node: cnt = sum over chunks (partial -> in-place exclusive chunk-prefix),
// dinv, and atomic-free graph ranges via sorted-batch boundary detection.
__global__ __launch_bounds__(256) void k_colsum(int* __restrict__ partial,
                                                const int* __restrict__ batch,
                                                int* __restrict__ cnt,
                                                float* __restrict__ dinv,
                                                unsigned* __restrict__ gstart,
                                                unsigned* __restrict__ gend) {
    int i = blockIdx.x * 256 + threadIdx.x;
    if (i >= N_NODES) return;
    int r  = i / RSPAN;
    int li = i - r * RSPAN;
    int sum = 0;
#pragma unroll
    for (int c = 0; c < NCHUNK; ++c) {
        int* p = partial + (size_t)(c * NRANGE + r) * RSPAN + li;
        int v = *p;
        *p = sum;                 // exclusive prefix over chunks
        sum += v;
    }
    cnt[i]  = sum;
    dinv[i] = rsqrtf((float)(sum + 1));   // +1 self-loop
    int b = batch[i];
    if (i == 0) gstart[b] = 0u;
    else {
        int pb = batch[i - 1];
        if (b != pb) { gstart[b] = (unsigned)i; gend[pb] = (unsigned)i; }
    }
    if (i == N_NODES - 1) gend[b] = (unsigned)N_NODES;
}

__global__ __launch_bounds__(256) void k_bsum(const int* __restrict__ cnt,
                                              int* __restrict__ bsum) {
    __shared__ int ws[4];
    int i = blockIdx.x * 256 + threadIdx.x;
    int v = (i < N_NODES) ? cnt[i] : 0;
#pragma unroll
    for (int o = 32; o > 0; o >>= 1) v += __shfl_down(v, o, 64);
    if ((threadIdx.x & 63) == 0) ws[threadIdx.x >> 6] = v;
    __syncthreads();
    if (threadIdx.x == 0) bsum[blockIdx.x] = ws[0] + ws[1] + ws[2] + ws[3];
}

__global__ void k_scan_bsum(const int* __restrict__ bsum, int* __restrict__ boff) {
    __shared__ int s[256];
    int t = threadIdx.x;
    int v = (t < NB) ? bsum[t] : 0;
    s[t] = v;
    __syncthreads();
    for (int o = 1; o < 256; o <<= 1) {
        int u = (t >= o) ? s[t - o] : 0;
        __syncthreads();
        s[t] += u;
        __syncthreads();
    }
    if (t < NB) boff[t] = s[t] - v;
}

__global__ __launch_bounds__(256) void k_rowptr(const int* __restrict__ cnt,
                                                const int* __restrict__ boff,
                                                int* __restrict__ row_ptr) {
    __shared__ int s[256];
    int t = threadIdx.x;
    int i = blockIdx.x * 256 + t;
    int v = (i < N_NODES) ? cnt[i] : 0;
    s[t] = v;
    __syncthreads();
    for (int o = 1; o < 256; o <<= 1) {
        int u = (t >= o) ? s[t - o] : 0;
        __syncthreads();
        s[t] += u;
        __syncthreads();
    }
    int excl = boff[blockIdx.x] + s[t] - v;
    if (i < N_NODES)       row_ptr[i] = excl;
    else if (i == N_NODES) row_ptr[N_NODES] = excl;
}

// CSR fill, LDS-cursor only (seeded row_ptr + chunk prefix -> no global atomics)
__global__ __launch_bounds__(256) void k_fill2(const int* __restrict__ src,
                                               const int* __restrict__ dst,
                                               const int* __restrict__ partial,
                                               const int* __restrict__ row_ptr,
                                               const float* __restrict__ dinv,
                                               int* __restrict__ col,
                                               float* __restrict__ wnorm) {
    __shared__ int   lcur[RSPAN];
    __shared__ float dl[RSPAN];
    const int r  = blockIdx.x & 15;
    const int c  = blockIdx.x >> 4;
    const int lo = r * RSPAN;
    const int* pp = partial + (size_t)(c * NRANGE + r) * RSPAN;
    for (int i = threadIdx.x; i < RSPAN; i += 256) {
        lcur[i] = row_ptr[lo + i] + pp[i];
        dl[i]   = dinv[lo + i];
    }
    __syncthreads();
    const int e0 = c * ESPAN;
    for (int e = e0 + threadIdx.x; e < e0 + ESPAN; e += 256) {
        int d = dst[e] - lo;
        int s = src[e];
        if ((unsigned)d < (unsigned)RSPAN) {
            int pos = atomicAdd(&lcur[d], 1);
            col[pos]   = s;
            wnorm[pos] = dinv[s] * dl[d];
        }
    }
}

// x (f32) -> xb (bf16), vectorized grid-stride
__global__ __launch_bounds__(256) void k_cvt(const float* __restrict__ x,
                                             unsigned short* __restrict__ xb) {
    const int total = N_NODES * 32;    // float4 groups
    for (int t = blockIdx.x * 256 + threadIdx.x; t < total; t += gridDim.x * 256) {
        float4 v = ((const float4*)x)[t];
        ushort4 o;
        o.x = f2b(v.x); o.y = f2b(v.y); o.z = f2b(v.z); o.w = f2b(v.w);
        ((ushort4*)xb)[t] = o;
    }
}

// ---------------------------------------------------------------- aggregation
// bf16 input rows (256B), fp32 accumulate, fp32 output. Half-wave per node:
// 2 nodes/wave, ushort4 (8B)/lane. 8-deep unrolled gather; OOB slots clamp
// to the row's last edge, weight 0.
__global__ __launch_bounds__(256) void k_agg_b(const unsigned short* __restrict__ hin,
                                               float* __restrict__ agg,
                                               const float* __restrict__ dinv,
                                               const int* __restrict__ row_ptr,
                                               const int* __restrict__ col,
                                               const float* __restrict__ wnorm) {
    const int wid  = blockIdx.x * 4 + (threadIdx.x >> 6);
    const int half = (threadIdx.x >> 5) & 1;
    const int node = wid * 2 + half;            // 6250*4*2 = 50000 exactly
    const int slot = threadIdx.x & 31;
    const ushort4* __restrict__ hin4 = (const ushort4*)hin + slot;

    float di = dinv[node];
    float4 v = b2f4(hin4[(size_t)node * 32]);
    float4 acc;
    acc.x = v.x * di * di; acc.y = v.y * di * di;   // self-loop
    acc.z = v.z * di * di; acc.w = v.w * di * di;

    int e0 = row_ptr[node], e1 = row_ptr[node + 1];
    const int last = e1 - 1;
    for (int e = e0; e < e1; e += 8) {
        int jj[8]; float wt[8];
#pragma unroll
        for (int i = 0; i < 8; ++i) {
            int ee = e + i;
            int cl = (ee <= last) ? ee : last;
            jj[i] = col[cl];
            wt[i] = (ee <= last) ? wnorm[cl] : 0.f;
        }
        ushort4 u[8];
#pragma unroll
        for (int i = 0; i < 8; ++i) u[i] = hin4[(size_t)jj[i] * 32];
#pragma unroll
        for (int i = 0; i < 8; ++i) {
            float4 f = b2f4(u[i]);
            acc.x += f.x * wt[i]; acc.y += f.y * wt[i];
            acc.z += f.z * wt[i]; acc.w += f.w * wt[i];
        }
    }
    ((float4*)agg)[(size_t)node * 32 + slot] = acc;
}

// ---------------------------------------------------------------- GEMM + bias + relu
// out(bf16) = relu(A(f32) @ W + b). Full W in LDS (64KB). 64-row tile, 256
// threads, 8 rows x 4 cols/thread. A read from global with row-group broadcast
// (L1-resident), double-buffered in named reg arrays (static idx only).
__global__ __launch_bounds__(256, 2) void k_gemm(const float* __restrict__ A,
                                                 const float* __restrict__ W,
                                                 const float* __restrict__ bias,
                                                 unsigned short* __restrict__ out) {
    __shared__ float4 Wl[DIM * 32];     // [k][c4], 65536 B

    const int tid = threadIdx.x;
    const int tc  = tid & 31;
    const int tr  = tid >> 5;
    const int rb  = blockIdx.x * 64;

    const float4* Wg = (const float4*)W;
#pragma unroll
    for (int i = 0; i < 16; ++i) Wl[tid + i * 256] = Wg[tid + i * 256];
    __syncthreads();

    const float4* ap[8];
#pragma unroll
    for (int r = 0; r < 8; ++r) {
        int crow = rb + tr * 8 + r;
        if (crow > N_NODES - 1) crow = N_NODES - 1;   // clamp loads; store guarded
        ap[r] = (const float4*)A + (size_t)crow * 32;
    }

    float acc[8][4] = {};
    float4 a0[8], a1[8];
#pragma unroll
    for (int r = 0; r < 8; ++r) a0[r] = ap[r][0];

#define GEMM_STEP(AF, PF, K4)                                             \
    {                                                                     \
        _Pragma("unroll")                                                 \
        for (int r = 0; r < 8; ++r) PF[r] = ap[r][(K4) + 1];              \
        float4 w0 = Wl[((K4) * 4 + 0) * 32 + tc];                         \
        float4 w1 = Wl[((K4) * 4 + 1) * 32 + tc];                         \
        float4 w2 = Wl[((K4) * 4 + 2) * 32 + tc];                         \
        float4 w3 = Wl[((K4) * 4 + 3) * 32 + tc];                         \
        _Pragma("unroll")                                                 \
        for (int r = 0; r < 8; ++r) {                                     \
            acc[r][0] += AF[r].x * w0.x; acc[r][1] += AF[r].x * w0.y;     \
            acc[r][2] += AF[r].x * w0.z; acc[r][3] += AF[r].x * w0.w;     \
            acc[r][0] += AF[r].y * w1.x; acc[r][1] += AF[r].y * w1.y;     \
            acc[r][2] += AF[r].y * w1.z; acc[r][3] += AF[r].y * w1.w;     \
            acc[r][0] += AF[r].z * w2.x; acc[r][1] += AF[r].z * w2.y;     \
            acc[r][2] += AF[r].z * w2.z; acc[r][3] += AF[r].z * w2.w;     \
            acc[r][0] += AF[r].w * w3.x; acc[r][1] += AF[r].w * w3.y;     \
            acc[r][2] += AF[r].w * w3.z; acc[r][3] += AF[r].w * w3.w;     \
        }                                                                 \
    }

    // final prefetch reads 16B past row 49999 -> stays inside d_ws: safe.
    for (int k8 = 0; k8 < 16; ++k8) {
        GEMM_STEP(a0, a1, 2 * k8)
        GEMM_STEP(a1, a0, 2 * k8 + 1)
    }
#undef GEMM_STEP

    float4 bv = ((const float4*)bias)[tc];
#pragma unroll
    for (int r = 0; r < 8; ++r) {
        int grow = rb + tr * 8 + r;
        if (grow < N_NODES) {
            ushort4 o;
            o.x = f2b(fmaxf(acc[r][0] + bv.x, 0.f));
            o.y = f2b(fmaxf(acc[r][1] + bv.y, 0.f));
            o.z = f2b(fmaxf(acc[r][2] + bv.z, 0.f));
            o.w = f2b(fmaxf(acc[r][3] + bv.w, 0.f));
            ((ushort4*)out)[(size_t)grow * 32 + tc] = o;
        }
    }
}

// ---------------------------------------------------------------- pooling (bf16 in)
// empty graphs have gstart==gend==0 -> loop body skipped.
__global__ __launch_bounds__(512) void k_pool_b(const unsigned short* __restrict__ h,
                                                const unsigned* __restrict__ gstart,
                                                const unsigned* __restrict__ gend,
                                                float* __restrict__ out, int layer) {
    __shared__ float4 red[16][32];
    int g    = blockIdx.x;
    int slot = threadIdx.x & 31;
    int way  = threadIdx.x >> 5;
    unsigned s = gstart[g], e = gend[g];
    float4 sum = make_float4(0.f, 0.f, 0.f, 0.f);
    for (unsigned i = s + way; i < e; i += 16) {
        float4 v = b2f4(((const ushort4*)h)[(size_t)i * 32 + slot]);
        sum.x += v.x; sum.y += v.y; sum.z += v.z; sum.w += v.w;
    }
    red[way][slot] = sum;
    __syncthreads();
    if (threadIdx.x < 32) {
        float4 t = red[0][slot];
#pragma unroll
        for (int wy = 1; wy < 16; ++wy) {
            float4 v = red[wy][slot];
            t.x += v.x; t.y += v.y; t.z += v.z; t.w += v.w;
        }
        *(float4*)&out[(size_t)g * (N_LAYERS * DIM) + layer * DIM + slot * 4] = t;
    }
}

// ---------------------------------------------------------------- launch

extern "C" void kernel_launch(void* const* d_in, const int* in_sizes, int n_in,
                              void* d_out, int out_size, void* d_ws, size_t ws_size,
                              hipStream_t stream) {
    const float* x    = (const float*)d_in[0];
    const int*   ei   = (const int*)d_in[1];
    const int*   bat  = (const int*)d_in[2];
    const float* Ws   = (const float*)d_in[3];
    const float* bs   = (const float*)d_in[4];
    float*       outp = (float*)d_out;

    const int* srcp = ei;
    const int* dstp = ei + N_EDGES;

    char* base = (char*)d_ws;
    size_t off = 0;
    float*          hP      = (float*)(base + off);          off += (size_t)N_NODES * DIM * 4;  // agg out, f32
    unsigned short* xb      = (unsigned short*)(base + off); off += (size_t)N_NODES * DIM * 2;
    unsigned short* hB0     = (unsigned short*)(base + off); off += (size_t)N_NODES * DIM * 2;
    unsigned short* hB1     = (unsigned short*)(base + off); off += (size_t)N_NODES * DIM * 2;
    float*          dinv    = (float*)(base + off);          off += (size_t)N_NODES * 4;
    int*            cnt     = (int*)(base + off);            off += (size_t)N_NODES * 4;
    int*            row_ptr = (int*)(base + off);            off += 200016;
    int*            col     = (int*)(base + off);            off += (size_t)N_EDGES * 4;
    float*          wnorm   = (float*)(base + off);          off += (size_t)N_EDGES * 4;
    int*            partial = (int*)(base + off);            off += (size_t)NCHUNK * NRANGE * RSPAN * 4;  // 3.2MB
    int*            bsum    = (int*)(base + off);            off += 1024;
    int*            boff    = (int*)(base + off);            off += 1024;
    unsigned*       gstart  = (unsigned*)(base + off);       off += 2048;
    unsigned*       gend    = (unsigned*)(base + off);       off += 2048;

    k_cvt<<<2048, 256, 0, stream>>>(x, xb);
    k_hist<<<NRANGE * NCHUNK, 256, 0, stream>>>(dstp, partial, gstart, gend);
    k_colsum<<<NB, 256, 0, stream>>>(partial, bat, cnt, dinv, gstart, gend);
    k_bsum<<<NB, 256, 0, stream>>>(cnt, bsum);
    k_scan_bsum<<<1, 256, 0, stream>>>(bsum, boff);
    k_rowptr<<<NB, 256, 0, stream>>>(cnt, boff, row_ptr);
    k_fill2<<<NRANGE * NCHUNK, 256, 0, stream>>>(srcp, dstp, partial, row_ptr, dinv,
                                                 col, wnorm);

    const int BAGG  = 6250;                   // 6250 * 4 waves * 2 nodes = 50000
    const int BGEMM = (N_NODES + 63) / 64;    // 782

    const unsigned short* hin = xb;
    unsigned short* houts[N_LAYERS] = { hB0, hB1, hB0, hB1, hB0 };
    for (int l = 0; l < N_LAYERS; ++l) {
        unsigned short* ho = houts[l];
        k_agg_b<<<BAGG, 256, 0, stream>>>(hin, hP, dinv, row_ptr, col, wnorm);
        k_gemm<<<BGEMM, 256, 0, stream>>>(hP, Ws + (size_t)l * DIM * DIM,
                                          bs + (size_t)l * DIM, ho);
        k_pool_b<<<N_GRAPHS, 512, 0, stream>>>(ho, gstart, gend, outp, l);
        hin = ho;
    }
}

// Round 8
// 423.433 us; speedup vs baseline: 1.2028x; 1.2028x over previous
//
#include <hip/hip_runtime.h>

#define N_NODES  50000
#define N_EDGES  600000
#define DIM      128
#define N_LAYERS 5
#define N_GRAPHS 512
#define NB       ((N_NODES + 255) / 256)   // 196
#define NRANGE   16
#define RSPAN    3125                      // 16 * 3125 = 50000
#define NCHUNK   64
#define ESPAN    9375                      // 64 * 9375 = 600000

// bf16 <-> f32 bit helpers (RNE)
__device__ __forceinline__ unsigned short f2b(float f) {
    unsigned u = __float_as_uint(f);
    return (unsigned short)((u + 0x7FFFu + ((u >> 16) & 1u)) >> 16);
}
__device__ __forceinline__ float4 b2f4(ushort4 u) {
    float4 c;
    c.x = __uint_as_float((unsigned)u.x << 16);
    c.y = __uint_as_float((unsigned)u.y << 16);
    c.z = __uint_as_float((unsigned)u.z << 16);
    c.w = __uint_as_float((unsigned)u.w << 16);
    return c;
}

// ---------------------------------------------------------------- preprocess
// CSR build with ZERO global atomics: 16 node-ranges x 64 edge-chunks.

// partial[c][r][i] = #edges in chunk c with dst == r*RSPAN+i  (LDS histogram)
__global__ __launch_bounds__(256) void k_hist(const int* __restrict__ dst,
                                              unsigned short* __restrict__ partial,
                                              unsigned* __restrict__ gstart,
                                              unsigned* __restrict__ gend) {
    __shared__ int histo[RSPAN];
    const int r  = blockIdx.x & 15;
    const int c  = blockIdx.x >> 4;
    const int lo = r * RSPAN;
    for (int i = threadIdx.x; i < RSPAN; i += 256) histo[i] = 0;
    if (blockIdx.x == 0) {
        for (int i = threadIdx.x; i < N_GRAPHS; i += 256) { gstart[i] = 0u; gend[i] = 0u; }
    }
    __syncthreads();
    const int e0 = c * ESPAN;
    for (int e = e0 + threadIdx.x; e < e0 + ESPAN; e += 256) {
        int d = dst[e] - lo;
        if ((unsigned)d < (unsigned)RSPAN) atomicAdd(&histo[d], 1);
    }
    __syncthreads();
    unsigned short* p = partial + (size_t)(c * NRANGE + r) * RSPAN;
    for (int i = threadIdx.x; i < RSPAN; i += 256) p[i] = (unsigned short)histo[i];
}

// per node: cnt = sum over chunks (partial -> in-place exclusive chunk-prefix),
// dinv, and atomic-free graph ranges via sorted-batch boundary detection.
__global__ __launch_bounds__(256) void k_colsum(unsigned short* __restrict__ partial,
                                                const int* __restrict__ batch,
                                                int* __restrict__ cnt,
                                                float* __restrict__ dinv,
                                                unsigned* __restrict__ gstart,
                                                unsigned* __restrict__ gend) {
    int i = blockIdx.x * 256 + threadIdx.x;
    if (i >= N_NODES) return;
    int r  = i / RSPAN;
    int li = i - r * RSPAN;
    int sum = 0;
#pragma unroll 4
    for (int c = 0; c < NCHUNK; ++c) {
        unsigned short* p = partial + (size_t)(c * NRANGE + r) * RSPAN + li;
        int v = *p;
        *p = (unsigned short)sum;     // exclusive prefix over chunks (fits u16)
        sum += v;
    }
    cnt[i]  = sum;
    dinv[i] = rsqrtf((float)(sum + 1));   // +1 self-loop
    int b = batch[i];
    if (i == 0) gstart[b] = 0u;
    else {
        int pb = batch[i - 1];
        if (b != pb) { gstart[b] = (unsigned)i; gend[pb] = (unsigned)i; }
    }
    if (i == N_NODES - 1) gend[b] = (unsigned)N_NODES;
}

__global__ __launch_bounds__(256) void k_bsum(const int* __restrict__ cnt,
                                              int* __restrict__ bsum) {
    __shared__ int ws[4];
    int i = blockIdx.x * 256 + threadIdx.x;
    int v = (i < N_NODES) ? cnt[i] : 0;
#pragma unroll
    for (int o = 32; o > 0; o >>= 1) v += __shfl_down(v, o, 64);
    if ((threadIdx.x & 63) == 0) ws[threadIdx.x >> 6] = v;
    __syncthreads();
    if (threadIdx.x == 0) bsum[blockIdx.x] = ws[0] + ws[1] + ws[2] + ws[3];
}

__global__ void k_scan_bsum(const int* __restrict__ bsum, int* __restrict__ boff) {
    __shared__ int s[256];
    int t = threadIdx.x;
    int v = (t < NB) ? bsum[t] : 0;
    s[t] = v;
    __syncthreads();
    for (int o = 1; o < 256; o <<= 1) {
        int u = (t >= o) ? s[t - o] : 0;
        __syncthreads();
        s[t] += u;
        __syncthreads();
    }
    if (t < NB) boff[t] = s[t] - v;
}

__global__ __launch_bounds__(256) void k_rowptr(const int* __restrict__ cnt,
                                                const int* __restrict__ boff,
                                                int* __restrict__ row_ptr) {
    __shared__ int s[256];
    int t = threadIdx.x;
    int i = blockIdx.x * 256 + t;
    int v = (i < N_NODES) ? cnt[i] : 0;
    s[t] = v;
    __syncthreads();
    for (int o = 1; o < 256; o <<= 1) {
        int u = (t >= o) ? s[t - o] : 0;
        __syncthreads();
        s[t] += u;
        __syncthreads();
    }
    int excl = boff[blockIdx.x] + s[t] - v;
    if (i < N_NODES)       row_ptr[i] = excl;
    else if (i == N_NODES) row_ptr[N_NODES] = excl;
}

// CSR fill, LDS-cursor only (seeded row_ptr + chunk prefix -> no global atomics)
__global__ __launch_bounds__(256) void k_fill2(const int* __restrict__ src,
                                               const int* __restrict__ dst,
                                               const unsigned short* __restrict__ partial,
                                               const int* __restrict__ row_ptr,
                                               const float* __restrict__ dinv,
                                               int* __restrict__ col,
                                               float* __restrict__ wnorm) {
    __shared__ int   lcur[RSPAN];
    __shared__ float dl[RSPAN];
    const int r  = blockIdx.x & 15;
    const int c  = blockIdx.x >> 4;
    const int lo = r * RSPAN;
    const unsigned short* pp = partial + (size_t)(c * NRANGE + r) * RSPAN;
    for (int i = threadIdx.x; i < RSPAN; i += 256) {
        lcur[i] = row_ptr[lo + i] + (int)pp[i];
        dl[i]   = dinv[lo + i];
    }
    __syncthreads();
    const int e0 = c * ESPAN;
    for (int e = e0 + threadIdx.x; e < e0 + ESPAN; e += 256) {
        int d = dst[e] - lo;
        int s = src[e];
        if ((unsigned)d < (unsigned)RSPAN) {
            int pos = atomicAdd(&lcur[d], 1);
            col[pos]   = s;
            wnorm[pos] = dinv[s] * dl[d];
        }
    }
}

// x (f32) -> xb (bf16), vectorized grid-stride
__global__ __launch_bounds__(256) void k_cvt(const float* __restrict__ x,
                                             unsigned short* __restrict__ xb) {
    const int total = N_NODES * 32;    // float4 groups
    for (int t = blockIdx.x * 256 + threadIdx.x; t < total; t += gridDim.x * 256) {
        float4 v = ((const float4*)x)[t];
        ushort4 o;
        o.x = f2b(v.x); o.y = f2b(v.y); o.z = f2b(v.z); o.w = f2b(v.w);
        ((ushort4*)xb)[t] = o;
    }
}

// ---------------------------------------------------------------- aggregation
// bf16 input rows (256B), fp32 accumulate, fp32 output. Half-wave per node:
// 2 nodes/wave, ushort4 (8B)/lane. 8-deep unrolled gather; OOB slots clamp
// to the row's last edge, weight 0.
__global__ __launch_bounds__(256) void k_agg_b(const unsigned short* __restrict__ hin,
                                               float* __restrict__ agg,
                                               const float* __restrict__ dinv,
                                               const int* __restrict__ row_ptr,
                                               const int* __restrict__ col,
                                               const float* __restrict__ wnorm) {
    const int wid  = blockIdx.x * 4 + (threadIdx.x >> 6);
    const int half = (threadIdx.x >> 5) & 1;
    const int node = wid * 2 + half;            // 6250*4*2 = 50000 exactly
    const int slot = threadIdx.x & 31;
    const ushort4* __restrict__ hin4 = (const ushort4*)hin + slot;

    float di = dinv[node];
    float4 v = b2f4(hin4[(size_t)node * 32]);
    float4 acc;
    acc.x = v.x * di * di; acc.y = v.y * di * di;   // self-loop
    acc.z = v.z * di * di; acc.w = v.w * di * di;

    int e0 = row_ptr[node], e1 = row_ptr[node + 1];
    const int last = e1 - 1;
    for (int e = e0; e < e1; e += 8) {
        int jj[8]; float wt[8];
#pragma unroll
        for (int i = 0; i < 8; ++i) {
            int ee = e + i;
            int cl = (ee <= last) ? ee : last;
            jj[i] = col[cl];
            wt[i] = (ee <= last) ? wnorm[cl] : 0.f;
        }
        ushort4 u[8];
#pragma unroll
        for (int i = 0; i < 8; ++i) u[i] = hin4[(size_t)jj[i] * 32];
#pragma unroll
        for (int i = 0; i < 8; ++i) {
            float4 f = b2f4(u[i]);
            acc.x += f.x * wt[i]; acc.y += f.y * wt[i];
            acc.z += f.z * wt[i]; acc.w += f.w * wt[i];
        }
    }
    ((float4*)agg)[(size_t)node * 32 + slot] = acc;
}

// ---------------------------------------------------------------- GEMM + bias + relu
// out(bf16) = relu(A(f32) @ W + b). Full W in LDS (64KB). 64-row tile, 256
// threads, 8 rows x 4 cols/thread. A read from global with row-group broadcast
// (L1-resident), double-buffered in named reg arrays (static idx only).
__global__ __launch_bounds__(256, 2) void k_gemm(const float* __restrict__ A,
                                                 const float* __restrict__ W,
                                                 const float* __restrict__ bias,
                                                 unsigned short* __restrict__ out) {
    __shared__ float4 Wl[DIM * 32];     // [k][c4], 65536 B

    const int tid = threadIdx.x;
    const int tc  = tid & 31;
    const int tr  = tid >> 5;
    const int rb  = blockIdx.x * 64;

    const float4* Wg = (const float4*)W;
#pragma unroll
    for (int i = 0; i < 16; ++i) Wl[tid + i * 256] = Wg[tid + i * 256];
    __syncthreads();

    const float4* ap[8];
#pragma unroll
    for (int r = 0; r < 8; ++r) {
        int crow = rb + tr * 8 + r;
        if (crow > N_NODES - 1) crow = N_NODES - 1;   // clamp loads; store guarded
        ap[r] = (const float4*)A + (size_t)crow * 32;
    }

    float acc[8][4] = {};
    float4 a0[8], a1[8];
#pragma unroll
    for (int r = 0; r < 8; ++r) a0[r] = ap[r][0];

#define GEMM_STEP(AF, PF, K4)                                             \
    {                                                                     \
        _Pragma("unroll")                                                 \
        for (int r = 0; r < 8; ++r) PF[r] = ap[r][(K4) + 1];              \
        float4 w0 = Wl[((K4) * 4 + 0) * 32 + tc];                         \
        float4 w1 = Wl[((K4) * 4 + 1) * 32 + tc];                         \
        float4 w2 = Wl[((K4) * 4 + 2) * 32 + tc];                         \
        float4 w3 = Wl[((K4) * 4 + 3) * 32 + tc];                         \
        _Pragma("unroll")                                                 \
        for (int r = 0; r < 8; ++r) {                                     \
            acc[r][0] += AF[r].x * w0.x; acc[r][1] += AF[r].x * w0.y;     \
            acc[r][2] += AF[r].x * w0.z; acc[r][3] += AF[r].x * w0.w;     \
            acc[r][0] += AF[r].y * w1.x; acc[r][1] += AF[r].y * w1.y;     \
            acc[r][2] += AF[r].y * w1.z; acc[r][3] += AF[r].y * w1.w;     \
            acc[r][0] += AF[r].z * w2.x; acc[r][1] += AF[r].z * w2.y;     \
            acc[r][2] += AF[r].z * w2.z; acc[r][3] += AF[r].z * w2.w;     \
            acc[r][0] += AF[r].w * w3.x; acc[r][1] += AF[r].w * w3.y;     \
            acc[r][2] += AF[r].w * w3.z; acc[r][3] += AF[r].w * w3.w;     \
        }                                                                 \
    }

    // final prefetch reads 16B past row 49999 -> stays inside d_ws: safe.
    for (int k8 = 0; k8 < 16; ++k8) {
        GEMM_STEP(a0, a1, 2 * k8)
        GEMM_STEP(a1, a0, 2 * k8 + 1)
    }
#undef GEMM_STEP

    float4 bv = ((const float4*)bias)[tc];
#pragma unroll
    for (int r = 0; r < 8; ++r) {
        int grow = rb + tr * 8 + r;
        if (grow < N_NODES) {
            ushort4 o;
            o.x = f2b(fmaxf(acc[r][0] + bv.x, 0.f));
            o.y = f2b(fmaxf(acc[r][1] + bv.y, 0.f));
            o.z = f2b(fmaxf(acc[r][2] + bv.z, 0.f));
            o.w = f2b(fmaxf(acc[r][3] + bv.w, 0.f));
            ((ushort4*)out)[(size_t)grow * 32 + tc] = o;
        }
    }
}

// ---------------------------------------------------------------- pooling (bf16 in)
// empty graphs have gstart==gend==0 -> loop body skipped.
__global__ __launch_bounds__(512) void k_pool_b(const unsigned short* __restrict__ h,
                                                const unsigned* __restrict__ gstart,
                                                const unsigned* __restrict__ gend,
                                                float* __restrict__ out, int layer) {
    __shared__ float4 red[16][32];
    int g    = blockIdx.x;
    int slot = threadIdx.x & 31;
    int way  = threadIdx.x >> 5;
    unsigned s = gstart[g], e = gend[g];
    float4 sum = make_float4(0.f, 0.f, 0.f, 0.f);
    for (unsigned i = s + way; i < e; i += 16) {
        float4 v = b2f4(((const ushort4*)h)[(size_t)i * 32 + slot]);
        sum.x += v.x; sum.y += v.y; sum.z += v.z; sum.w += v.w;
    }
    red[way][slot] = sum;
    __syncthreads();
    if (threadIdx.x < 32) {
        float4 t = red[0][slot];
#pragma unroll
        for (int wy = 1; wy < 16; ++wy) {
            float4 v = red[wy][slot];
            t.x += v.x; t.y += v.y; t.z += v.z; t.w += v.w;
        }
        *(float4*)&out[(size_t)g * (N_LAYERS * DIM) + layer * DIM + slot * 4] = t;
    }
}

// ---------------------------------------------------------------- launch

extern "C" void kernel_launch(void* const* d_in, const int* in_sizes, int n_in,
                              void* d_out, int out_size, void* d_ws, size_t ws_size,
                              hipStream_t stream) {
    const float* x    = (const float*)d_in[0];
    const int*   ei   = (const int*)d_in[1];
    const int*   bat  = (const int*)d_in[2];
    const float* Ws   = (const float*)d_in[3];
    const float* bs   = (const float*)d_in[4];
    float*       outp = (float*)d_out;

    const int* srcp = ei;
    const int* dstp = ei + N_EDGES;

    char* base = (char*)d_ws;
    size_t off = 0;
    float*          hP      = (float*)(base + off);          off += (size_t)N_NODES * DIM * 4;  // agg out, f32
    unsigned short* xb      = (unsigned short*)(base + off); off += (size_t)N_NODES * DIM * 2;
    unsigned short* hB0     = (unsigned short*)(base + off); off += (size_t)N_NODES * DIM * 2;
    unsigned short* hB1     = (unsigned short*)(base + off); off += (size_t)N_NODES * DIM * 2;
    float*          dinv    = (float*)(base + off);          off += (size_t)N_NODES * 4;
    int*            cnt     = (int*)(base + off);            off += (size_t)N_NODES * 4;
    int*            row_ptr = (int*)(base + off);            off += 200016;
    int*            col     = (int*)(base + off);            off += (size_t)N_EDGES * 4;
    float*          wnorm   = (float*)(base + off);          off += (size_t)N_EDGES * 4;
    unsigned short* partial = (unsigned short*)(base + off); off += (size_t)NCHUNK * NRANGE * RSPAN * 2;  // 6.4MB
    int*            bsum    = (int*)(base + off);            off += 1024;
    int*            boff    = (int*)(base + off);            off += 1024;
    unsigned*       gstart  = (unsigned*)(base + off);       off += 2048;
    unsigned*       gend    = (unsigned*)(base + off);       off += 2048;

    k_cvt<<<2048, 256, 0, stream>>>(x, xb);
    k_hist<<<NRANGE * NCHUNK, 256, 0, stream>>>(dstp, partial, gstart, gend);
    k_colsum<<<NB, 256, 0, stream>>>(partial, bat, cnt, dinv, gstart, gend);
    k_bsum<<<NB, 256, 0, stream>>>(cnt, bsum);
    k_scan_bsum<<<1, 256, 0, stream>>>(bsum, boff);
    k_rowptr<<<NB, 256, 0, stream>>>(cnt, boff, row_ptr);
    k_fill2<<<NRANGE * NCHUNK, 256, 0, stream>>>(srcp, dstp, partial, row_ptr, dinv,
                                                 col, wnorm);

    const int BAGG  = 6250;                   // 6250 * 4 waves * 2 nodes = 50000
    const int BGEMM = (N_NODES + 63) / 64;    // 782

    const unsigned short* hin = xb;
    unsigned short* houts[N_LAYERS] = { hB0, hB1, hB0, hB1, hB0 };
    for (int l = 0; l < N_LAYERS; ++l) {
        unsigned short* ho = houts[l];
        k_agg_b<<<BAGG, 256, 0, stream>>>(hin, hP, dinv, row_ptr, col, wnorm);
        k_gemm<<<BGEMM, 256, 0, stream>>>(hP, Ws + (size_t)l * DIM * DIM,
                                          bs + (size_t)l * DIM, ho);
        k_pool_b<<<N_GRAPHS, 512, 0, stream>>>(ho, gstart, gend, outp, l);
        hin = ho;
    }
}

// Round 9
// 417.861 us; speedup vs baseline: 1.2188x; 1.0133x over previous
//
#include <hip/hip_runtime.h>

#define N_NODES  50000
#define N_EDGES  600000
#define DIM      128
#define N_LAYERS 5
#define N_GRAPHS 512
#define NB       ((N_NODES + 255) / 256)   // 196
#define NRANGE   16
#define RSPAN    3125                      // 16 * 3125 = 50000
#define NCHUNK   64
#define ESPAN    9375                      // 64 * 9375 = 600000

// bf16 <-> f32 bit helpers (RNE)
__device__ __forceinline__ unsigned short f2b(float f) {
    unsigned u = __float_as_uint(f);
    return (unsigned short)((u + 0x7FFFu + ((u >> 16) & 1u)) >> 16);
}
__device__ __forceinline__ float4 b2f4(ushort4 u) {
    float4 c;
    c.x = __uint_as_float((unsigned)u.x << 16);
    c.y = __uint_as_float((unsigned)u.y << 16);
    c.z = __uint_as_float((unsigned)u.z << 16);
    c.w = __uint_as_float((unsigned)u.w << 16);
    return c;
}

// ---------------------------------------------------------------- preprocess
// CSR build with ZERO global atomics: 16 node-ranges x 64 edge-chunks.

__global__ __launch_bounds__(256) void k_hist(const int* __restrict__ dst,
                                              unsigned short* __restrict__ partial,
                                              unsigned* __restrict__ gstart,
                                              unsigned* __restrict__ gend) {
    __shared__ int histo[RSPAN];
    const int r  = blockIdx.x & 15;
    const int c  = blockIdx.x >> 4;
    const int lo = r * RSPAN;
    for (int i = threadIdx.x; i < RSPAN; i += 256) histo[i] = 0;
    if (blockIdx.x == 0) {
        for (int i = threadIdx.x; i < N_GRAPHS; i += 256) { gstart[i] = 0u; gend[i] = 0u; }
    }
    __syncthreads();
    const int e0 = c * ESPAN;
    for (int e = e0 + threadIdx.x; e < e0 + ESPAN; e += 256) {
        int d = dst[e] - lo;
        if ((unsigned)d < (unsigned)RSPAN) atomicAdd(&histo[d], 1);
    }
    __syncthreads();
    unsigned short* p = partial + (size_t)(c * NRANGE + r) * RSPAN;
    for (int i = threadIdx.x; i < RSPAN; i += 256) p[i] = (unsigned short)histo[i];
}

__global__ __launch_bounds__(256) void k_colsum(unsigned short* __restrict__ partial,
                                                const int* __restrict__ batch,
                                                int* __restrict__ cnt,
                                                float* __restrict__ dinv,
                                                unsigned* __restrict__ gstart,
                                                unsigned* __restrict__ gend) {
    int i = blockIdx.x * 256 + threadIdx.x;
    if (i >= N_NODES) return;
    int r  = i / RSPAN;
    int li = i - r * RSPAN;
    int sum = 0;
#pragma unroll 4
    for (int c = 0; c < NCHUNK; ++c) {
        unsigned short* p = partial + (size_t)(c * NRANGE + r) * RSPAN + li;
        int v = *p;
        *p = (unsigned short)sum;     // exclusive prefix over chunks (fits u16)
        sum += v;
    }
    cnt[i]  = sum;
    dinv[i] = rsqrtf((float)(sum + 1));   // +1 self-loop
    int b = batch[i];
    if (i == 0) gstart[b] = 0u;
    else {
        int pb = batch[i - 1];
        if (b != pb) { gstart[b] = (unsigned)i; gend[pb] = (unsigned)i; }
    }
    if (i == N_NODES - 1) gend[b] = (unsigned)N_NODES;
}

__global__ __launch_bounds__(256) void k_bsum(const int* __restrict__ cnt,
                                              int* __restrict__ bsum) {
    __shared__ int ws[4];
    int i = blockIdx.x * 256 + threadIdx.x;
    int v = (i < N_NODES) ? cnt[i] : 0;
#pragma unroll
    for (int o = 32; o > 0; o >>= 1) v += __shfl_down(v, o, 64);
    if ((threadIdx.x & 63) == 0) ws[threadIdx.x >> 6] = v;
    __syncthreads();
    if (threadIdx.x == 0) bsum[blockIdx.x] = ws[0] + ws[1] + ws[2] + ws[3];
}

__global__ void k_scan_bsum(const int* __restrict__ bsum, int* __restrict__ boff) {
    __shared__ int s[256];
    int t = threadIdx.x;
    int v = (t < NB) ? bsum[t] : 0;
    s[t] = v;
    __syncthreads();
    for (int o = 1; o < 256; o <<= 1) {
        int u = (t >= o) ? s[t - o] : 0;
        __syncthreads();
        s[t] += u;
        __syncthreads();
    }
    if (t < NB) boff[t] = s[t] - v;
}

__global__ __launch_bounds__(256) void k_rowptr(const int* __restrict__ cnt,
                                                const int* __restrict__ boff,
                                                int* __restrict__ row_ptr) {
    __shared__ int s[256];
    int t = threadIdx.x;
    int i = blockIdx.x * 256 + t;
    int v = (i < N_NODES) ? cnt[i] : 0;
    s[t] = v;
    __syncthreads();
    for (int o = 1; o < 256; o <<= 1) {
        int u = (t >= o) ? s[t - o] : 0;
        __syncthreads();
        s[t] += u;
        __syncthreads();
    }
    int excl = boff[blockIdx.x] + s[t] - v;
    if (i < N_NODES)       row_ptr[i] = excl;
    else if (i == N_NODES) row_ptr[N_NODES] = excl;
}

__global__ __launch_bounds__(256) void k_fill2(const int* __restrict__ src,
                                               const int* __restrict__ dst,
                                               const unsigned short* __restrict__ partial,
                                               const int* __restrict__ row_ptr,
                                               const float* __restrict__ dinv,
                                               int* __restrict__ col,
                                               float* __restrict__ wnorm) {
    __shared__ int   lcur[RSPAN];
    __shared__ float dl[RSPAN];
    const int r  = blockIdx.x & 15;
    const int c  = blockIdx.x >> 4;
    const int lo = r * RSPAN;
    const unsigned short* pp = partial + (size_t)(c * NRANGE + r) * RSPAN;
    for (int i = threadIdx.x; i < RSPAN; i += 256) {
        lcur[i] = row_ptr[lo + i] + (int)pp[i];
        dl[i]   = dinv[lo + i];
    }
    __syncthreads();
    const int e0 = c * ESPAN;
    for (int e = e0 + threadIdx.x; e < e0 + ESPAN; e += 256) {
        int d = dst[e] - lo;
        int s = src[e];
        if ((unsigned)d < (unsigned)RSPAN) {
            int pos = atomicAdd(&lcur[d], 1);
            col[pos]   = s;
            wnorm[pos] = dinv[s] * dl[d];
        }
    }
}

// x (f32) -> xb (bf16), vectorized grid-stride
__global__ __launch_bounds__(256) void k_cvt(const float* __restrict__ x,
                                             unsigned short* __restrict__ xb) {
    const int total = N_NODES * 32;    // float4 groups
    for (int t = blockIdx.x * 256 + threadIdx.x; t < total; t += gridDim.x * 256) {
        float4 v = ((const float4*)x)[t];
        ushort4 o;
        o.x = f2b(v.x); o.y = f2b(v.y); o.z = f2b(v.z); o.w = f2b(v.w);
        ((ushort4*)xb)[t] = o;
    }
}

// ---------------------------------------------------------------- aggregation
// bf16 input rows (256B), fp32 accumulate, fp32 output. Half-wave per node.
__global__ __launch_bounds__(256) void k_agg_b(const unsigned short* __restrict__ hin,
                                               float* __restrict__ agg,
                                               const float* __restrict__ dinv,
                                               const int* __restrict__ row_ptr,
                                               const int* __restrict__ col,
                                               const float* __restrict__ wnorm) {
    const int wid  = blockIdx.x * 4 + (threadIdx.x >> 6);
    const int half = (threadIdx.x >> 5) & 1;
    const int node = wid * 2 + half;            // 6250*4*2 = 50000 exactly
    const int slot = threadIdx.x & 31;
    const ushort4* __restrict__ hin4 = (const ushort4*)hin + slot;

    float di = dinv[node];
    float4 v = b2f4(hin4[(size_t)node * 32]);
    float4 acc;
    acc.x = v.x * di * di; acc.y = v.y * di * di;   // self-loop
    acc.z = v.z * di * di; acc.w = v.w * di * di;

    int e0 = row_ptr[node], e1 = row_ptr[node + 1];
    const int last = e1 - 1;
    for (int e = e0; e < e1; e += 8) {
        int jj[8]; float wt[8];
#pragma unroll
        for (int i = 0; i < 8; ++i) {
            int ee = e + i;
            int cl = (ee <= last) ? ee : last;
            jj[i] = col[cl];
            wt[i] = (ee <= last) ? wnorm[cl] : 0.f;
        }
        ushort4 u[8];
#pragma unroll
        for (int i = 0; i < 8; ++i) u[i] = hin4[(size_t)jj[i] * 32];
#pragma unroll
        for (int i = 0; i < 8; ++i) {
            float4 f = b2f4(u[i]);
            acc.x += f.x * wt[i]; acc.y += f.y * wt[i];
            acc.z += f.z * wt[i]; acc.w += f.w * wt[i];
        }
    }
    ((float4*)agg)[(size_t)node * 32 + slot] = acc;
}

// ---------------------------------------------------------------- GEMM + bias + relu
// out(bf16) = relu(A(f32) @ W + b). 128-row x 64-col tile: W-half in LDS
// (32KB -> 4 blocks/CU vs 2 at 64KB). 256 threads, 8 rows x 4 cols/thread
// (same per-thread shape/regs as the 108-VGPR round-8 codegen). A read from
// global with row-group broadcast, double-buffered in named reg arrays.
__global__ __launch_bounds__(256, 2) void k_gemm(const float* __restrict__ A,
                                                 const float* __restrict__ W,
                                                 const float* __restrict__ bias,
                                                 unsigned short* __restrict__ out) {
    __shared__ float4 Wl[DIM * 16];     // [k][c4-half], 32768 B

    const int tid = threadIdx.x;
    const int tc  = tid & 15;           // 16 col groups x 4 cols = 64 cols
    const int tr  = tid >> 4;           // 16 row groups x 8 rows = 128 rows
    const int rt  = blockIdx.x >> 1;
    const int ch  = blockIdx.x & 1;     // column half
    const int rb  = rt * 128;

    // stage W half: k=0..127, cols ch*64..ch*64+63 (2048 float4, 8/thread)
    {
        const float4* Wg = (const float4*)W;
#pragma unroll
        for (int i = 0; i < 8; ++i) {
            int idx = tid + i * 256;
            int k = idx >> 4, j = idx & 15;
            Wl[idx] = Wg[k * 32 + ch * 16 + j];
        }
    }
    __syncthreads();

    const float4* ap[8];
#pragma unroll
    for (int r = 0; r < 8; ++r) {
        int crow = rb + tr * 8 + r;
        if (crow > N_NODES - 1) crow = N_NODES - 1;   // clamp loads; store guarded
        ap[r] = (const float4*)A + (size_t)crow * 32;
    }

    float acc[8][4] = {};
    float4 a0[8], a1[8];
#pragma unroll
    for (int r = 0; r < 8; ++r) a0[r] = ap[r][0];

#define GEMM_STEP(AF, PF, K4)                                             \
    {                                                                     \
        _Pragma("unroll")                                                 \
        for (int r = 0; r < 8; ++r) PF[r] = ap[r][(K4) + 1];              \
        float4 w0 = Wl[((K4) * 4 + 0) * 16 + tc];                         \
        float4 w1 = Wl[((K4) * 4 + 1) * 16 + tc];                         \
        float4 w2 = Wl[((K4) * 4 + 2) * 16 + tc];                         \
        float4 w3 = Wl[((K4) * 4 + 3) * 16 + tc];                         \
        _Pragma("unroll")                                                 \
        for (int r = 0; r < 8; ++r) {                                     \
            acc[r][0] += AF[r].x * w0.x; acc[r][1] += AF[r].x * w0.y;     \
            acc[r][2] += AF[r].x * w0.z; acc[r][3] += AF[r].x * w0.w;     \
            acc[r][0] += AF[r].y * w1.x; acc[r][1] += AF[r].y * w1.y;     \
            acc[r][2] += AF[r].y * w1.z; acc[r][3] += AF[r].y * w1.w;     \
            acc[r][0] += AF[r].z * w2.x; acc[r][1] += AF[r].z * w2.y;     \
            acc[r][2] += AF[r].z * w2.z; acc[r][3] += AF[r].z * w2.w;     \
            acc[r][0] += AF[r].w * w3.x; acc[r][1] += AF[r].w * w3.y;     \
            acc[r][2] += AF[r].w * w3.z; acc[r][3] += AF[r].w * w3.w;     \
        }                                                                 \
    }

    // final prefetch reads 16B past row 49999 -> stays inside d_ws: safe.
    for (int k8 = 0; k8 < 16; ++k8) {
        GEMM_STEP(a0, a1, 2 * k8)
        GEMM_STEP(a1, a0, 2 * k8 + 1)
    }
#undef GEMM_STEP

    float4 bv = ((const float4*)bias)[ch * 16 + tc];
#pragma unroll
    for (int r = 0; r < 8; ++r) {
        int grow = rb + tr * 8 + r;
        if (grow < N_NODES) {
            ushort4 o;
            o.x = f2b(fmaxf(acc[r][0] + bv.x, 0.f));
            o.y = f2b(fmaxf(acc[r][1] + bv.y, 0.f));
            o.z = f2b(fmaxf(acc[r][2] + bv.z, 0.f));
            o.w = f2b(fmaxf(acc[r][3] + bv.w, 0.f));
            ((ushort4*)out)[(size_t)grow * 32 + ch * 16 + tc] = o;
        }
    }
}

// ---------------------------------------------------------------- pooling (bf16 in)
__global__ __launch_bounds__(512) void k_pool_b(const unsigned short* __restrict__ h,
                                                const unsigned* __restrict__ gstart,
                                                const unsigned* __restrict__ gend,
                                                float* __restrict__ out, int layer) {
    __shared__ float4 red[16][32];
    int g    = blockIdx.x;
    int slot = threadIdx.x & 31;
    int way  = threadIdx.x >> 5;
    unsigned s = gstart[g], e = gend[g];
    float4 sum = make_float4(0.f, 0.f, 0.f, 0.f);
    for (unsigned i = s + way; i < e; i += 16) {
        float4 v = b2f4(((const ushort4*)h)[(size_t)i * 32 + slot]);
        sum.x += v.x; sum.y += v.y; sum.z += v.z; sum.w += v.w;
    }
    red[way][slot] = sum;
    __syncthreads();
    if (threadIdx.x < 32) {
        float4 t = red[0][slot];
#pragma unroll
        for (int wy = 1; wy < 16; ++wy) {
            float4 v = red[wy][slot];
            t.x += v.x; t.y += v.y; t.z += v.z; t.w += v.w;
        }
        *(float4*)&out[(size_t)g * (N_LAYERS * DIM) + layer * DIM + slot * 4] = t;
    }
}

// ---------------------------------------------------------------- launch

extern "C" void kernel_launch(void* const* d_in, const int* in_sizes, int n_in,
                              void* d_out, int out_size, void* d_ws, size_t ws_size,
                              hipStream_t stream) {
    const float* x    = (const float*)d_in[0];
    const int*   ei   = (const int*)d_in[1];
    const int*   bat  = (const int*)d_in[2];
    const float* Ws   = (const float*)d_in[3];
    const float* bs   = (const float*)d_in[4];
    float*       outp = (float*)d_out;

    const int* srcp = ei;
    const int* dstp = ei + N_EDGES;

    char* base = (char*)d_ws;
    size_t off = 0;
    float*          hP      = (float*)(base + off);          off += (size_t)N_NODES * DIM * 4;  // agg out, f32
    unsigned short* xb      = (unsigned short*)(base + off); off += (size_t)N_NODES * DIM * 2;
    unsigned short* hB0     = (unsigned short*)(base + off); off += (size_t)N_NODES * DIM * 2;
    unsigned short* hB1     = (unsigned short*)(base + off); off += (size_t)N_NODES * DIM * 2;
    float*          dinv    = (float*)(base + off);          off += (size_t)N_NODES * 4;
    int*            cnt     = (int*)(base + off);            off += (size_t)N_NODES * 4;
    int*            row_ptr = (int*)(base + off);            off += 200016;
    int*            col     = (int*)(base + off);            off += (size_t)N_EDGES * 4;
    float*          wnorm   = (float*)(base + off);          off += (size_t)N_EDGES * 4;
    unsigned short* partial = (unsigned short*)(base + off); off += (size_t)NCHUNK * NRANGE * RSPAN * 2;  // 6.4MB
    int*            bsum    = (int*)(base + off);            off += 1024;
    int*            boff    = (int*)(base + off);            off += 1024;
    unsigned*       gstart  = (unsigned*)(base + off);       off += 2048;
    unsigned*       gend    = (unsigned*)(base + off);       off += 2048;

    k_cvt<<<2048, 256, 0, stream>>>(x, xb);
    k_hist<<<NRANGE * NCHUNK, 256, 0, stream>>>(dstp, partial, gstart, gend);
    k_colsum<<<NB, 256, 0, stream>>>(partial, bat, cnt, dinv, gstart, gend);
    k_bsum<<<NB, 256, 0, stream>>>(cnt, bsum);
    k_scan_bsum<<<1, 256, 0, stream>>>(bsum, boff);
    k_rowptr<<<NB, 256, 0, stream>>>(cnt, boff, row_ptr);
    k_fill2<<<NRANGE * NCHUNK, 256, 0, stream>>>(srcp, dstp, partial, row_ptr, dinv,
                                                 col, wnorm);

    const int BAGG  = 6250;                      // 6250 * 4 waves * 2 nodes = 50000
    const int BGEMM = ((N_NODES + 127) / 128) * 2;  // 391 row-tiles x 2 col halves = 782

    const unsigned short* hin = xb;
    unsigned short* houts[N_LAYERS] = { hB0, hB1, hB0, hB1, hB0 };
    for (int l = 0; l < N_LAYERS; ++l) {
        unsigned short* ho = houts[l];
        k_agg_b<<<BAGG, 256, 0, stream>>>(hin, hP, dinv, row_ptr, col, wnorm);
        k_gemm<<<BGEMM, 256, 0, stream>>>(hP, Ws + (size_t)l * DIM * DIM,
                                          bs + (size_t)l * DIM, ho);
        k_pool_b<<<N_GRAPHS, 512, 0, stream>>>(ho, gstart, gend, outp, l);
        hin = ho;
    }
}

// Round 10
// 333.660 us; speedup vs baseline: 1.5264x; 1.2524x over previous
//
#include <hip/hip_runtime.h>

#define N_NODES  50000
#define N_EDGES  600000
#define DIM      128
#define N_LAYERS 5
#define N_GRAPHS 512
#define NB       ((N_NODES + 255) / 256)   // 196
#define NRANGE   16
#define RSPAN    3125                      // 16 * 3125 = 50000
#define NCHUNK   64
#define ESPAN    9375                      // 64 * 9375 = 600000

typedef __attribute__((ext_vector_type(8))) short short8;
typedef __attribute__((ext_vector_type(4))) float f32x4;

// bf16 <-> f32 bit helpers (RNE)
__device__ __forceinline__ unsigned short f2b(float f) {
    unsigned u = __float_as_uint(f);
    return (unsigned short)((u + 0x7FFFu + ((u >> 16) & 1u)) >> 16);
}
__device__ __forceinline__ float4 b2f4(ushort4 u) {
    float4 c;
    c.x = __uint_as_float((unsigned)u.x << 16);
    c.y = __uint_as_float((unsigned)u.y << 16);
    c.z = __uint_as_float((unsigned)u.z << 16);
    c.w = __uint_as_float((unsigned)u.w << 16);
    return c;
}

// ---------------------------------------------------------------- preprocess
// CSR build with ZERO global atomics: 16 node-ranges x 64 edge-chunks.

__global__ __launch_bounds__(256) void k_hist(const int* __restrict__ dst,
                                              unsigned short* __restrict__ partial,
                                              unsigned* __restrict__ gstart,
                                              unsigned* __restrict__ gend) {
    __shared__ int histo[RSPAN];
    const int r  = blockIdx.x & 15;
    const int c  = blockIdx.x >> 4;
    const int lo = r * RSPAN;
    for (int i = threadIdx.x; i < RSPAN; i += 256) histo[i] = 0;
    if (blockIdx.x == 0) {
        for (int i = threadIdx.x; i < N_GRAPHS; i += 256) { gstart[i] = 0u; gend[i] = 0u; }
    }
    __syncthreads();
    const int e0 = c * ESPAN;
    for (int e = e0 + threadIdx.x; e < e0 + ESPAN; e += 256) {
        int d = dst[e] - lo;
        if ((unsigned)d < (unsigned)RSPAN) atomicAdd(&histo[d], 1);
    }
    __syncthreads();
    unsigned short* p = partial + (size_t)(c * NRANGE + r) * RSPAN;
    for (int i = threadIdx.x; i < RSPAN; i += 256) p[i] = (unsigned short)histo[i];
}

__global__ __launch_bounds__(256) void k_colsum(unsigned short* __restrict__ partial,
                                                const int* __restrict__ batch,
                                                int* __restrict__ cnt,
                                                float* __restrict__ dinv,
                                                unsigned* __restrict__ gstart,
                                                unsigned* __restrict__ gend) {
    int i = blockIdx.x * 256 + threadIdx.x;
    if (i >= N_NODES) return;
    int r  = i / RSPAN;
    int li = i - r * RSPAN;
    int sum = 0;
#pragma unroll 4
    for (int c = 0; c < NCHUNK; ++c) {
        unsigned short* p = partial + (size_t)(c * NRANGE + r) * RSPAN + li;
        int v = *p;
        *p = (unsigned short)sum;     // exclusive prefix over chunks (fits u16)
        sum += v;
    }
    cnt[i]  = sum;
    dinv[i] = rsqrtf((float)(sum + 1));   // +1 self-loop
    int b = batch[i];
    if (i == 0) gstart[b] = 0u;
    else {
        int pb = batch[i - 1];
        if (b != pb) { gstart[b] = (unsigned)i; gend[pb] = (unsigned)i; }
    }
    if (i == N_NODES - 1) gend[b] = (unsigned)N_NODES;
}

__global__ __launch_bounds__(256) void k_bsum(const int* __restrict__ cnt,
                                              int* __restrict__ bsum) {
    __shared__ int ws[4];
    int i = blockIdx.x * 256 + threadIdx.x;
    int v = (i < N_NODES) ? cnt[i] : 0;
#pragma unroll
    for (int o = 32; o > 0; o >>= 1) v += __shfl_down(v, o, 64);
    if ((threadIdx.x & 63) == 0) ws[threadIdx.x >> 6] = v;
    __syncthreads();
    if (threadIdx.x == 0) bsum[blockIdx.x] = ws[0] + ws[1] + ws[2] + ws[3];
}

__global__ void k_scan_bsum(const int* __restrict__ bsum, int* __restrict__ boff) {
    __shared__ int s[256];
    int t = threadIdx.x;
    int v = (t < NB) ? bsum[t] : 0;
    s[t] = v;
    __syncthreads();
    for (int o = 1; o < 256; o <<= 1) {
        int u = (t >= o) ? s[t - o] : 0;
        __syncthreads();
        s[t] += u;
        __syncthreads();
    }
    if (t < NB) boff[t] = s[t] - v;
}

__global__ __launch_bounds__(256) void k_rowptr(const int* __restrict__ cnt,
                                                const int* __restrict__ boff,
                                                int* __restrict__ row_ptr) {
    __shared__ int s[256];
    int t = threadIdx.x;
    int i = blockIdx.x * 256 + t;
    int v = (i < N_NODES) ? cnt[i] : 0;
    s[t] = v;
    __syncthreads();
    for (int o = 1; o < 256; o <<= 1) {
        int u = (t >= o) ? s[t - o] : 0;
        __syncthreads();
        s[t] += u;
        __syncthreads();
    }
    int excl = boff[blockIdx.x] + s[t] - v;
    if (i < N_NODES)       row_ptr[i] = excl;
    else if (i == N_NODES) row_ptr[N_NODES] = excl;
}

__global__ __launch_bounds__(256) void k_fill2(const int* __restrict__ src,
                                               const int* __restrict__ dst,
                                               const unsigned short* __restrict__ partial,
                                               const int* __restrict__ row_ptr,
                                               const float* __restrict__ dinv,
                                               int* __restrict__ col,
                                               float* __restrict__ wnorm) {
    __shared__ int   lcur[RSPAN];
    __shared__ float dl[RSPAN];
    const int r  = blockIdx.x & 15;
    const int c  = blockIdx.x >> 4;
    const int lo = r * RSPAN;
    const unsigned short* pp = partial + (size_t)(c * NRANGE + r) * RSPAN;
    for (int i = threadIdx.x; i < RSPAN; i += 256) {
        lcur[i] = row_ptr[lo + i] + (int)pp[i];
        dl[i]   = dinv[lo + i];
    }
    __syncthreads();
    const int e0 = c * ESPAN;
    for (int e = e0 + threadIdx.x; e < e0 + ESPAN; e += 256) {
        int d = dst[e] - lo;
        int s = src[e];
        if ((unsigned)d < (unsigned)RSPAN) {
            int pos = atomicAdd(&lcur[d], 1);
            col[pos]   = s;
            wnorm[pos] = dinv[s] * dl[d];
        }
    }
}

// x (f32) -> xb (bf16), vectorized grid-stride
__global__ __launch_bounds__(256) void k_cvt(const float* __restrict__ x,
                                             unsigned short* __restrict__ xb) {
    const int total = N_NODES * 32;    // float4 groups
    for (int t = blockIdx.x * 256 + threadIdx.x; t < total; t += gridDim.x * 256) {
        float4 v = ((const float4*)x)[t];
        ushort4 o;
        o.x = f2b(v.x); o.y = f2b(v.y); o.z = f2b(v.z); o.w = f2b(v.w);
        ((ushort4*)xb)[t] = o;
    }
}

// W[5][128][128] f32 -> fragment-ordered bf16 hi/lo for mfma_f32_16x16x32_bf16.
// Element index within layer: ((ntile*4 + kstep)*64 + lane)*8 + j, value =
// W[k][n] with k = kstep*32 + (lane>>4)*8 + j, n = ntile*16 + (lane&15).
__global__ __launch_bounds__(256) void k_prepw(const float* __restrict__ W,
                                               unsigned short* __restrict__ wh,
                                               unsigned short* __restrict__ wl) {
    int t = blockIdx.x * 256 + threadIdx.x;          // (l, nt, ks, lane)
    if (t >= N_LAYERS * 8 * 4 * 64) return;
    int lane = t & 63;
    int ks   = (t >> 6) & 3;
    int nt   = (t >> 8) & 7;
    int l    = t >> 11;
    int n  = nt * 16 + (lane & 15);
    int kb = ks * 32 + (lane >> 4) * 8;
    size_t obase = (size_t)t * 8;
#pragma unroll
    for (int j = 0; j < 8; ++j) {
        float f = W[(size_t)l * 16384 + (kb + j) * DIM + n];
        unsigned short hi = f2b(f);
        float rf = f - __uint_as_float((unsigned)hi << 16);
        wh[obase + j] = hi;
        wl[obase + j] = f2b(rf);
    }
}

// ---------------------------------------------------------------- aggregation
// bf16 input rows (256B), fp32 accumulate, fp32 output. Half-wave per node.
__global__ __launch_bounds__(256) void k_agg_b(const unsigned short* __restrict__ hin,
                                               float* __restrict__ agg,
                                               const float* __restrict__ dinv,
                                               const int* __restrict__ row_ptr,
                                               const int* __restrict__ col,
                                               const float* __restrict__ wnorm) {
    const int wid  = blockIdx.x * 4 + (threadIdx.x >> 6);
    const int half = (threadIdx.x >> 5) & 1;
    const int node = wid * 2 + half;            // 6250*4*2 = 50000 exactly
    const int slot = threadIdx.x & 31;
    const ushort4* __restrict__ hin4 = (const ushort4*)hin + slot;

    float di = dinv[node];
    float4 v = b2f4(hin4[(size_t)node * 32]);
    float4 acc;
    acc.x = v.x * di * di; acc.y = v.y * di * di;   // self-loop
    acc.z = v.z * di * di; acc.w = v.w * di * di;

    int e0 = row_ptr[node], e1 = row_ptr[node + 1];
    const int last = e1 - 1;
    for (int e = e0; e < e1; e += 8) {
        int jj[8]; float wt[8];
#pragma unroll
        for (int i = 0; i < 8; ++i) {
            int ee = e + i;
            int cl = (ee <= last) ? ee : last;
            jj[i] = col[cl];
            wt[i] = (ee <= last) ? wnorm[cl] : 0.f;
        }
        ushort4 u[8];
#pragma unroll
        for (int i = 0; i < 8; ++i) u[i] = hin4[(size_t)jj[i] * 32];
#pragma unroll
        for (int i = 0; i < 8; ++i) {
            float4 f = b2f4(u[i]);
            acc.x += f.x * wt[i]; acc.y += f.y * wt[i];
            acc.z += f.z * wt[i]; acc.w += f.w * wt[i];
        }
    }
    ((float4*)agg)[(size_t)node * 32 + slot] = acc;
}

// ---------------------------------------------------------------- GEMM (MFMA)
// out(bf16) = relu(A(f32) @ W + b). 64 rows/block, 4 waves x 16 rows.
// A split in-register into bf16 hi (truncation) + lo (residual RNE); W
// pre-split hi/lo, fragment-ordered, staged in LDS (64KB). 3 MFMAs per
// 16x16 tile: hi*hi + lo*hi + hi*lo  (~fp32-equivalent precision).
// Layouts (guide §3): A row=lane&15, k=(lane>>4)*8+j; B col=lane&15, same k;
// C/D col=lane&15, row=(lane>>4)*4+reg.
__global__ __launch_bounds__(256, 2) void k_gemm_mfma(const float* __restrict__ A,
                                                      const unsigned short* __restrict__ wh,
                                                      const unsigned short* __restrict__ wl,
                                                      const float* __restrict__ bias,
                                                      unsigned short* __restrict__ out) {
    __shared__ short Whl[16384];   // 32KB hi
    __shared__ short Wll[16384];   // 32KB lo

    const int tid  = threadIdx.x;
    const int wv   = tid >> 6;
    const int lane = tid & 63;
    const int rb   = blockIdx.x * 64;

    // stage fragment-ordered W hi/lo (2048 float4 each, coalesced)
    {
        const float4* GH = (const float4*)wh;
        const float4* GL = (const float4*)wl;
        float4* SH = (float4*)Whl;
        float4* SL = (float4*)Wll;
#pragma unroll
        for (int i = 0; i < 8; ++i) SH[tid + i * 256] = GH[tid + i * 256];
#pragma unroll
        for (int i = 0; i < 8; ++i) SL[tid + i * 256] = GL[tid + i * 256];
    }

    // A loads: row = rb + wv*16 + (lane&15), 32B at k-offset (lane>>4)*8 per kstep
    int rowA = rb + wv * 16 + (lane & 15);
    if (rowA > N_NODES - 1) rowA = N_NODES - 1;     // clamp loads; store guarded
    const float* Ab = A + (size_t)rowA * DIM + (lane >> 4) * 8;
    float4 af0[4], af1[4];
#pragma unroll
    for (int ks = 0; ks < 4; ++ks) {
        af0[ks] = *(const float4*)(Ab + ks * 32);
        af1[ks] = *(const float4*)(Ab + ks * 32 + 4);
    }

    __syncthreads();   // W staged

    // split A into hi/lo bf16 fragments
    short8 ahi[4], alo[4];
#pragma unroll
    for (int ks = 0; ks < 4; ++ks) {
        float a8[8] = { af0[ks].x, af0[ks].y, af0[ks].z, af0[ks].w,
                        af1[ks].x, af1[ks].y, af1[ks].z, af1[ks].w };
#pragma unroll
        for (int j = 0; j < 8; ++j) {
            unsigned u = __float_as_uint(a8[j]);
            unsigned short hi = (unsigned short)(u >> 16);       // truncation
            float rf = a8[j] - __uint_as_float((unsigned)hi << 16);
            ahi[ks][j] = (short)hi;
            alo[ks][j] = (short)f2b(rf);
        }
    }

    f32x4 acc[8] = {};
    const short8* WH = (const short8*)Whl;
    const short8* WL = (const short8*)Wll;
#pragma unroll
    for (int nt = 0; nt < 8; ++nt) {
#pragma unroll
        for (int ks = 0; ks < 4; ++ks) {
            short8 bh = WH[(nt * 4 + ks) * 64 + lane];
            short8 bl = WL[(nt * 4 + ks) * 64 + lane];
            acc[nt] = __builtin_amdgcn_mfma_f32_16x16x32_bf16(ahi[ks], bh, acc[nt], 0, 0, 0);
            acc[nt] = __builtin_amdgcn_mfma_f32_16x16x32_bf16(alo[ks], bh, acc[nt], 0, 0, 0);
            acc[nt] = __builtin_amdgcn_mfma_f32_16x16x32_bf16(ahi[ks], bl, acc[nt], 0, 0, 0);
        }
    }

    // epilogue: C col = lane&15, row = (lane>>4)*4 + r
    const int rowC = rb + wv * 16 + (lane >> 4) * 4;
    const int cl   = lane & 15;
#pragma unroll
    for (int nt = 0; nt < 8; ++nt) {
        float bv = bias[nt * 16 + cl];
#pragma unroll
        for (int r = 0; r < 4; ++r) {
            int row = rowC + r;
            if (row < N_NODES)
                out[(size_t)row * DIM + nt * 16 + cl] = f2b(fmaxf(acc[nt][r] + bv, 0.f));
        }
    }
}

// ---------------------------------------------------------------- pooling (bf16 in)
__global__ __launch_bounds__(512) void k_pool_b(const unsigned short* __restrict__ h,
                                                const unsigned* __restrict__ gstart,
                                                const unsigned* __restrict__ gend,
                                                float* __restrict__ out, int layer) {
    __shared__ float4 red[16][32];
    int g    = blockIdx.x;
    int slot = threadIdx.x & 31;
    int way  = threadIdx.x >> 5;
    unsigned s = gstart[g], e = gend[g];
    float4 sum = make_float4(0.f, 0.f, 0.f, 0.f);
    for (unsigned i = s + way; i < e; i += 16) {
        float4 v = b2f4(((const ushort4*)h)[(size_t)i * 32 + slot]);
        sum.x += v.x; sum.y += v.y; sum.z += v.z; sum.w += v.w;
    }
    red[way][slot] = sum;
    __syncthreads();
    if (threadIdx.x < 32) {
        float4 t = red[0][slot];
#pragma unroll
        for (int wy = 1; wy < 16; ++wy) {
            float4 v = red[wy][slot];
            t.x += v.x; t.y += v.y; t.z += v.z; t.w += v.w;
        }
        *(float4*)&out[(size_t)g * (N_LAYERS * DIM) + layer * DIM + slot * 4] = t;
    }
}

// ---------------------------------------------------------------- launch

extern "C" void kernel_launch(void* const* d_in, const int* in_sizes, int n_in,
                              void* d_out, int out_size, void* d_ws, size_t ws_size,
                              hipStream_t stream) {
    const float* x    = (const float*)d_in[0];
    const int*   ei   = (const int*)d_in[1];
    const int*   bat  = (const int*)d_in[2];
    const float* Ws   = (const float*)d_in[3];
    const float* bs   = (const float*)d_in[4];
    float*       outp = (float*)d_out;

    const int* srcp = ei;
    const int* dstp = ei + N_EDGES;

    char* base = (char*)d_ws;
    size_t off = 0;
    float*          hP      = (float*)(base + off);          off += (size_t)N_NODES * DIM * 4;  // agg out, f32
    unsigned short* xb      = (unsigned short*)(base + off); off += (size_t)N_NODES * DIM * 2;
    unsigned short* hB0     = (unsigned short*)(base + off); off += (size_t)N_NODES * DIM * 2;
    unsigned short* hB1     = (unsigned short*)(base + off); off += (size_t)N_NODES * DIM * 2;
    float*          dinv    = (float*)(base + off);          off += (size_t)N_NODES * 4;
    int*            cnt     = (int*)(base + off);            off += (size_t)N_NODES * 4;
    int*            row_ptr = (int*)(base + off);            off += 200016;
    int*            col     = (int*)(base + off);            off += (size_t)N_EDGES * 4;
    float*          wnorm   = (float*)(base + off);          off += (size_t)N_EDGES * 4;
    unsigned short* partial = (unsigned short*)(base + off); off += (size_t)NCHUNK * NRANGE * RSPAN * 2;  // 6.4MB
    unsigned short* wfh     = (unsigned short*)(base + off); off += (size_t)N_LAYERS * 16384 * 2;
    unsigned short* wfl     = (unsigned short*)(base + off); off += (size_t)N_LAYERS * 16384 * 2;
    int*            bsum    = (int*)(base + off);            off += 1024;
    int*            boff    = (int*)(base + off);            off += 1024;
    unsigned*       gstart  = (unsigned*)(base + off);       off += 2048;
    unsigned*       gend    = (unsigned*)(base + off);       off += 2048;

    k_cvt<<<2048, 256, 0, stream>>>(x, xb);
    k_prepw<<<40, 256, 0, stream>>>(Ws, wfh, wfl);
    k_hist<<<NRANGE * NCHUNK, 256, 0, stream>>>(dstp, partial, gstart, gend);
    k_colsum<<<NB, 256, 0, stream>>>(partial, bat, cnt, dinv, gstart, gend);
    k_bsum<<<NB, 256, 0, stream>>>(cnt, bsum);
    k_scan_bsum<<<1, 256, 0, stream>>>(bsum, boff);
    k_rowptr<<<NB, 256, 0, stream>>>(cnt, boff, row_ptr);
    k_fill2<<<NRANGE * NCHUNK, 256, 0, stream>>>(srcp, dstp, partial, row_ptr, dinv,
                                                 col, wnorm);

    const int BAGG  = 6250;                      // 6250 * 4 waves * 2 nodes = 50000
    const int BGEMM = (N_NODES + 63) / 64;       // 782

    const unsigned short* hin = xb;
    unsigned short* houts[N_LAYERS] = { hB0, hB1, hB0, hB1, hB0 };
    for (int l = 0; l < N_LAYERS; ++l) {
        unsigned short* ho = houts[l];
        k_agg_b<<<BAGG, 256, 0, stream>>>(hin, hP, dinv, row_ptr, col, wnorm);
        k_gemm_mfma<<<BGEMM, 256, 0, stream>>>(hP, wfh + (size_t)l * 16384,
                                               wfl + (size_t)l * 16384,
                                               bs + (size_t)l * DIM, ho);
        k_pool_b<<<N_GRAPHS, 512, 0, stream>>>(ho, gstart, gend, outp, l);
        hin = ho;
    }
}

// Round 11
// 304.331 us; speedup vs baseline: 1.6735x; 1.0964x over previous
//
#include <hip/hip_runtime.h>

#define N_NODES  50000
#define N_EDGES  600000
#define DIM      128
#define N_LAYERS 5
#define N_GRAPHS 512
#define NB       ((N_NODES + 255) / 256)   // 196
#define NRANGE   16
#define RSPAN    3125                      // 16 * 3125 = 50000
#define NCHUNK   64
#define ESPAN    9375                      // 64 * 9375 = 600000

typedef __attribute__((ext_vector_type(8))) short short8;
typedef __attribute__((ext_vector_type(4))) float f32x4;

// bf16 <-> f32 bit helpers (RNE)
__device__ __forceinline__ unsigned short f2b(float f) {
    unsigned u = __float_as_uint(f);
    return (unsigned short)((u + 0x7FFFu + ((u >> 16) & 1u)) >> 16);
}
__device__ __forceinline__ float4 b2f4(ushort4 u) {
    float4 c;
    c.x = __uint_as_float((unsigned)u.x << 16);
    c.y = __uint_as_float((unsigned)u.y << 16);
    c.z = __uint_as_float((unsigned)u.z << 16);
    c.w = __uint_as_float((unsigned)u.w << 16);
    return c;
}

// ---------------------------------------------------------------- preprocess
// CSR build with ZERO global atomics: 16 node-ranges x 64 edge-chunks.

__global__ __launch_bounds__(256) void k_hist(const int* __restrict__ dst,
                                              unsigned short* __restrict__ partial,
                                              unsigned* __restrict__ gstart,
                                              unsigned* __restrict__ gend) {
    __shared__ int histo[RSPAN];
    const int r  = blockIdx.x & 15;
    const int c  = blockIdx.x >> 4;
    const int lo = r * RSPAN;
    for (int i = threadIdx.x; i < RSPAN; i += 256) histo[i] = 0;
    if (blockIdx.x == 0) {
        for (int i = threadIdx.x; i < N_GRAPHS; i += 256) { gstart[i] = 0u; gend[i] = 0u; }
    }
    __syncthreads();
    const int e0 = c * ESPAN;
    for (int e = e0 + threadIdx.x; e < e0 + ESPAN; e += 256) {
        int d = dst[e] - lo;
        if ((unsigned)d < (unsigned)RSPAN) atomicAdd(&histo[d], 1);
    }
    __syncthreads();
    unsigned short* p = partial + (size_t)(c * NRANGE + r) * RSPAN;
    for (int i = threadIdx.x; i < RSPAN; i += 256) p[i] = (unsigned short)histo[i];
}

__global__ __launch_bounds__(256) void k_colsum(unsigned short* __restrict__ partial,
                                                const int* __restrict__ batch,
                                                int* __restrict__ cnt,
                                                float* __restrict__ dinv,
                                                unsigned* __restrict__ gstart,
                                                unsigned* __restrict__ gend) {
    int i = blockIdx.x * 256 + threadIdx.x;
    if (i >= N_NODES) return;
    int r  = i / RSPAN;
    int li = i - r * RSPAN;
    int sum = 0;
#pragma unroll 4
    for (int c = 0; c < NCHUNK; ++c) {
        unsigned short* p = partial + (size_t)(c * NRANGE + r) * RSPAN + li;
        int v = *p;
        *p = (unsigned short)sum;     // exclusive prefix over chunks (fits u16)
        sum += v;
    }
    cnt[i]  = sum;
    dinv[i] = rsqrtf((float)(sum + 1));   // +1 self-loop
    int b = batch[i];
    if (i == 0) gstart[b] = 0u;
    else {
        int pb = batch[i - 1];
        if (b != pb) { gstart[b] = (unsigned)i; gend[pb] = (unsigned)i; }
    }
    if (i == N_NODES - 1) gend[b] = (unsigned)N_NODES;
}

__global__ __launch_bounds__(256) void k_bsum(const int* __restrict__ cnt,
                                              int* __restrict__ bsum) {
    __shared__ int ws[4];
    int i = blockIdx.x * 256 + threadIdx.x;
    int v = (i < N_NODES) ? cnt[i] : 0;
#pragma unroll
    for (int o = 32; o > 0; o >>= 1) v += __shfl_down(v, o, 64);
    if ((threadIdx.x & 63) == 0) ws[threadIdx.x >> 6] = v;
    __syncthreads();
    if (threadIdx.x == 0) bsum[blockIdx.x] = ws[0] + ws[1] + ws[2] + ws[3];
}

__global__ void k_scan_bsum(const int* __restrict__ bsum, int* __restrict__ boff) {
    __shared__ int s[256];
    int t = threadIdx.x;
    int v = (t < NB) ? bsum[t] : 0;
    s[t] = v;
    __syncthreads();
    for (int o = 1; o < 256; o <<= 1) {
        int u = (t >= o) ? s[t - o] : 0;
        __syncthreads();
        s[t] += u;
        __syncthreads();
    }
    if (t < NB) boff[t] = s[t] - v;
}

__global__ __launch_bounds__(256) void k_rowptr(const int* __restrict__ cnt,
                                                const int* __restrict__ boff,
                                                int* __restrict__ row_ptr) {
    __shared__ int s[256];
    int t = threadIdx.x;
    int i = blockIdx.x * 256 + t;
    int v = (i < N_NODES) ? cnt[i] : 0;
    s[t] = v;
    __syncthreads();
    for (int o = 1; o < 256; o <<= 1) {
        int u = (t >= o) ? s[t - o] : 0;
        __syncthreads();
        s[t] += u;
        __syncthreads();
    }
    int excl = boff[blockIdx.x] + s[t] - v;
    if (i < N_NODES)       row_ptr[i] = excl;
    else if (i == N_NODES) row_ptr[N_NODES] = excl;
}

__global__ __launch_bounds__(256) void k_fill2(const int* __restrict__ src,
                                               const int* __restrict__ dst,
                                               const unsigned short* __restrict__ partial,
                                               const int* __restrict__ row_ptr,
                                               const float* __restrict__ dinv,
                                               int* __restrict__ col,
                                               float* __restrict__ wnorm) {
    __shared__ int   lcur[RSPAN];
    __shared__ float dl[RSPAN];
    const int r  = blockIdx.x & 15;
    const int c  = blockIdx.x >> 4;
    const int lo = r * RSPAN;
    const unsigned short* pp = partial + (size_t)(c * NRANGE + r) * RSPAN;
    for (int i = threadIdx.x; i < RSPAN; i += 256) {
        lcur[i] = row_ptr[lo + i] + (int)pp[i];
        dl[i]   = dinv[lo + i];
    }
    __syncthreads();
    const int e0 = c * ESPAN;
    for (int e = e0 + threadIdx.x; e < e0 + ESPAN; e += 256) {
        int d = dst[e] - lo;
        int s = src[e];
        if ((unsigned)d < (unsigned)RSPAN) {
            int pos = atomicAdd(&lcur[d], 1);
            col[pos]   = s;
            wnorm[pos] = dinv[s] * dl[d];
        }
    }
}

// x (f32) -> xb (bf16), vectorized grid-stride
__global__ __launch_bounds__(256) void k_cvt(const float* __restrict__ x,
                                             unsigned short* __restrict__ xb) {
    const int total = N_NODES * 32;    // float4 groups
    for (int t = blockIdx.x * 256 + threadIdx.x; t < total; t += gridDim.x * 256) {
        float4 v = ((const float4*)x)[t];
        ushort4 o;
        o.x = f2b(v.x); o.y = f2b(v.y); o.z = f2b(v.z); o.w = f2b(v.w);
        ((ushort4*)xb)[t] = o;
    }
}

// W[5][128][128] f32 -> fragment-ordered bf16 (RNE) for mfma_f32_16x16x32_bf16.
// Element index within layer: ((ntile*4 + kstep)*64 + lane)*8 + j, value =
// W[k][n] with k = kstep*32 + (lane>>4)*8 + j, n = ntile*16 + (lane&15).
__global__ __launch_bounds__(256) void k_prepw(const float* __restrict__ W,
                                               unsigned short* __restrict__ wh) {
    int t = blockIdx.x * 256 + threadIdx.x;          // (l, nt, ks, lane)
    if (t >= N_LAYERS * 8 * 4 * 64) return;
    int lane = t & 63;
    int ks   = (t >> 6) & 3;
    int nt   = (t >> 8) & 7;
    int l    = t >> 11;
    int n  = nt * 16 + (lane & 15);
    int kb = ks * 32 + (lane >> 4) * 8;
    size_t obase = (size_t)t * 8;
#pragma unroll
    for (int j = 0; j < 8; ++j) {
        float f = W[(size_t)l * 16384 + (kb + j) * DIM + n];
        wh[obase + j] = f2b(f);
    }
}

// ---------------------------------------------------------------- aggregation
// bf16 input rows (256B), fp32 accumulate, fp32 output. Half-wave per node.
__global__ __launch_bounds__(256) void k_agg_b(const unsigned short* __restrict__ hin,
                                               float* __restrict__ agg,
                                               const float* __restrict__ dinv,
                                               const int* __restrict__ row_ptr,
                                               const int* __restrict__ col,
                                               const float* __restrict__ wnorm) {
    const int wid  = blockIdx.x * 4 + (threadIdx.x >> 6);
    const int half = (threadIdx.x >> 5) & 1;
    const int node = wid * 2 + half;            // 6250*4*2 = 50000 exactly
    const int slot = threadIdx.x & 31;
    const ushort4* __restrict__ hin4 = (const ushort4*)hin + slot;

    float di = dinv[node];
    float4 v = b2f4(hin4[(size_t)node * 32]);
    float4 acc;
    acc.x = v.x * di * di; acc.y = v.y * di * di;   // self-loop
    acc.z = v.z * di * di; acc.w = v.w * di * di;

    int e0 = row_ptr[node], e1 = row_ptr[node + 1];
    const int last = e1 - 1;
    for (int e = e0; e < e1; e += 8) {
        int jj[8]; float wt[8];
#pragma unroll
        for (int i = 0; i < 8; ++i) {
            int ee = e + i;
            int cl = (ee <= last) ? ee : last;
            jj[i] = col[cl];
            wt[i] = (ee <= last) ? wnorm[cl] : 0.f;
        }
        ushort4 u[8];
#pragma unroll
        for (int i = 0; i < 8; ++i) u[i] = hin4[(size_t)jj[i] * 32];
#pragma unroll
        for (int i = 0; i < 8; ++i) {
            float4 f = b2f4(u[i]);
            acc.x += f.x * wt[i]; acc.y += f.y * wt[i];
            acc.z += f.z * wt[i]; acc.w += f.w * wt[i];
        }
    }
    ((float4*)agg)[(size_t)node * 32 + slot] = acc;
}

// ---------------------------------------------------------------- GEMM (MFMA)
// out(bf16) = relu(A(f32) @ W + b). 64 rows/block, 4 waves x 16 rows.
// A split in-register into bf16 hi (truncation) + lo (residual RNE):
// (A_hi + A_lo) @ W_hi  -> 2 MFMAs per 16x16 tile. W_hi (bf16 RNE) only,
// 32KB LDS; its residual term is ~10x below the bf16-h storage noise.
// Layouts (guide §3): A row=lane&15, k=(lane>>4)*8+j; B col=lane&15, same k;
// C/D col=lane&15, row=(lane>>4)*4+reg.
__global__ __launch_bounds__(256, 2) void k_gemm_mfma(const float* __restrict__ A,
                                                      const unsigned short* __restrict__ wh,
                                                      const float* __restrict__ bias,
                                                      unsigned short* __restrict__ out) {
    __shared__ short Whl[16384];   // 32KB, fragment-ordered W_hi

    const int tid  = threadIdx.x;
    const int wv   = tid >> 6;
    const int lane = tid & 63;
    const int rb   = blockIdx.x * 64;

    // stage fragment-ordered W_hi (2048 float4, coalesced, 8/thread)
    {
        const float4* GH = (const float4*)wh;
        float4* SH = (float4*)Whl;
#pragma unroll
        for (int i = 0; i < 8; ++i) SH[tid + i * 256] = GH[tid + i * 256];
    }

    // A loads: row = rb + wv*16 + (lane&15), 32B at k-offset (lane>>4)*8 per kstep
    int rowA = rb + wv * 16 + (lane & 15);
    if (rowA > N_NODES - 1) rowA = N_NODES - 1;     // clamp loads; store guarded
    const float* Ab = A + (size_t)rowA * DIM + (lane >> 4) * 8;
    float4 af0[4], af1[4];
#pragma unroll
    for (int ks = 0; ks < 4; ++ks) {
        af0[ks] = *(const float4*)(Ab + ks * 32);
        af1[ks] = *(const float4*)(Ab + ks * 32 + 4);
    }

    __syncthreads();   // W staged

    // split A into hi/lo bf16 fragments
    short8 ahi[4], alo[4];
#pragma unroll
    for (int ks = 0; ks < 4; ++ks) {
        float a8[8] = { af0[ks].x, af0[ks].y, af0[ks].z, af0[ks].w,
                        af1[ks].x, af1[ks].y, af1[ks].z, af1[ks].w };
#pragma unroll
        for (int j = 0; j < 8; ++j) {
            unsigned u = __float_as_uint(a8[j]);
            unsigned short hi = (unsigned short)(u >> 16);       // truncation
            float rf = a8[j] - __uint_as_float((unsigned)hi << 16);
            ahi[ks][j] = (short)hi;
            alo[ks][j] = (short)f2b(rf);
        }
    }

    f32x4 acc[8] = {};
    const short8* WH = (const short8*)Whl;
#pragma unroll
    for (int nt = 0; nt < 8; ++nt) {
#pragma unroll
        for (int ks = 0; ks < 4; ++ks) {
            short8 bh = WH[(nt * 4 + ks) * 64 + lane];
            acc[nt] = __builtin_amdgcn_mfma_f32_16x16x32_bf16(ahi[ks], bh, acc[nt], 0, 0, 0);
            acc[nt] = __builtin_amdgcn_mfma_f32_16x16x32_bf16(alo[ks], bh, acc[nt], 0, 0, 0);
        }
    }

    // epilogue: C col = lane&15, row = (lane>>4)*4 + r
    const int rowC = rb + wv * 16 + (lane >> 4) * 4;
    const int cl   = lane & 15;
#pragma unroll
    for (int nt = 0; nt < 8; ++nt) {
        float bv = bias[nt * 16 + cl];
#pragma unroll
        for (int r = 0; r < 4; ++r) {
            int row = rowC + r;
            if (row < N_NODES)
                out[(size_t)row * DIM + nt * 16 + cl] = f2b(fmaxf(acc[nt][r] + bv, 0.f));
        }
    }
}

// ---------------------------------------------------------------- pooling (bf16 in)
__global__ __launch_bounds__(512) void k_pool_b(const unsigned short* __restrict__ h,
                                                const unsigned* __restrict__ gstart,
                                                const unsigned* __restrict__ gend,
                                                float* __restrict__ out, int layer) {
    __shared__ float4 red[16][32];
    int g    = blockIdx.x;
    int slot = threadIdx.x & 31;
    int way  = threadIdx.x >> 5;
    unsigned s = gstart[g], e = gend[g];
    float4 sum = make_float4(0.f, 0.f, 0.f, 0.f);
    for (unsigned i = s + way; i < e; i += 16) {
        float4 v = b2f4(((const ushort4*)h)[(size_t)i * 32 + slot]);
        sum.x += v.x; sum.y += v.y; sum.z += v.z; sum.w += v.w;
    }
    red[way][slot] = sum;
    __syncthreads();
    if (threadIdx.x < 32) {
        float4 t = red[0][slot];
#pragma unroll
        for (int wy = 1; wy < 16; ++wy) {
            float4 v = red[wy][slot];
            t.x += v.x; t.y += v.y; t.z += v.z; t.w += v.w;
        }
        *(float4*)&out[(size_t)g * (N_LAYERS * DIM) + layer * DIM + slot * 4] = t;
    }
}

// ---------------------------------------------------------------- launch

extern "C" void kernel_launch(void* const* d_in, const int* in_sizes, int n_in,
                              void* d_out, int out_size, void* d_ws, size_t ws_size,
                              hipStream_t stream) {
    const float* x    = (const float*)d_in[0];
    const int*   ei   = (const int*)d_in[1];
    const int*   bat  = (const int*)d_in[2];
    const float* Ws   = (const float*)d_in[3];
    const float* bs   = (const float*)d_in[4];
    float*       outp = (float*)d_out;

    const int* srcp = ei;
    const int* dstp = ei + N_EDGES;

    char* base = (char*)d_ws;
    size_t off = 0;
    float*          hP      = (float*)(base + off);          off += (size_t)N_NODES * DIM * 4;  // agg out, f32
    unsigned short* xb      = (unsigned short*)(base + off); off += (size_t)N_NODES * DIM * 2;
    unsigned short* hB0     = (unsigned short*)(base + off); off += (size_t)N_NODES * DIM * 2;
    unsigned short* hB1     = (unsigned short*)(base + off); off += (size_t)N_NODES * DIM * 2;
    float*          dinv    = (float*)(base + off);          off += (size_t)N_NODES * 4;
    int*            cnt     = (int*)(base + off);            off += (size_t)N_NODES * 4;
    int*            row_ptr = (int*)(base + off);            off += 200016;
    int*            col     = (int*)(base + off);            off += (size_t)N_EDGES * 4;
    float*          wnorm   = (float*)(base + off);          off += (size_t)N_EDGES * 4;
    unsigned short* partial = (unsigned short*)(base + off); off += (size_t)NCHUNK * NRANGE * RSPAN * 2;  // 6.4MB
    unsigned short* wfh     = (unsigned short*)(base + off); off += (size_t)N_LAYERS * 16384 * 2;
    int*            bsum    = (int*)(base + off);            off += 1024;
    int*            boff    = (int*)(base + off);            off += 1024;
    unsigned*       gstart  = (unsigned*)(base + off);       off += 2048;
    unsigned*       gend    = (unsigned*)(base + off);       off += 2048;

    k_cvt<<<2048, 256, 0, stream>>>(x, xb);
    k_prepw<<<40, 256, 0, stream>>>(Ws, wfh);
    k_hist<<<NRANGE * NCHUNK, 256, 0, stream>>>(dstp, partial, gstart, gend);
    k_colsum<<<NB, 256, 0, stream>>>(partial, bat, cnt, dinv, gstart, gend);
    k_bsum<<<NB, 256, 0, stream>>>(cnt, bsum);
    k_scan_bsum<<<1, 256, 0, stream>>>(bsum, boff);
    k_rowptr<<<NB, 256, 0, stream>>>(cnt, boff, row_ptr);
    k_fill2<<<NRANGE * NCHUNK, 256, 0, stream>>>(srcp, dstp, partial, row_ptr, dinv,
                                                 col, wnorm);

    const int BAGG  = 6250;                      // 6250 * 4 waves * 2 nodes = 50000
    const int BGEMM = (N_NODES + 63) / 64;       // 782

    const unsigned short* hin = xb;
    unsigned short* houts[N_LAYERS] = { hB0, hB1, hB0, hB1, hB0 };
    for (int l = 0; l < N_LAYERS; ++l) {
        unsigned short* ho = houts[l];
        k_agg_b<<<BAGG, 256, 0, stream>>>(hin, hP, dinv, row_ptr, col, wnorm);
        k_gemm_mfma<<<BGEMM, 256, 0, stream>>>(hP, wfh + (size_t)l * 16384,
                                               bs + (size_t)l * DIM, ho);
        k_pool_b<<<N_GRAPHS, 512, 0, stream>>>(ho, gstart, gend, outp, l);
        hin = ho;
    }
}

// Round 12
// 278.752 us; speedup vs baseline: 1.8271x; 1.0918x over previous
//
#include <hip/hip_runtime.h>

#define N_NODES  50000
#define N_EDGES  600000
#define DIM      128
#define N_LAYERS 5
#define N_GRAPHS 512
#define NB       ((N_NODES + 255) / 256)   // 196
#define NRANGE   16
#define RSPAN    3125                      // 16 * 3125 = 50000
#define NCHUNK   64
#define ESPAN    9375                      // 64 * 9375 = 600000

typedef __attribute__((ext_vector_type(8))) short short8;
typedef __attribute__((ext_vector_type(4))) float f32x4;

// bf16 <-> f32 bit helpers (RNE)
__device__ __forceinline__ unsigned short f2b(float f) {
    unsigned u = __float_as_uint(f);
    return (unsigned short)((u + 0x7FFFu + ((u >> 16) & 1u)) >> 16);
}
__device__ __forceinline__ float4 b2f4(ushort4 u) {
    float4 c;
    c.x = __uint_as_float((unsigned)u.x << 16);
    c.y = __uint_as_float((unsigned)u.y << 16);
    c.z = __uint_as_float((unsigned)u.z << 16);
    c.w = __uint_as_float((unsigned)u.w << 16);
    return c;
}

// ---------------------------------------------------------------- preprocess
// CSR build with ZERO global atomics: 16 node-ranges x 64 edge-chunks.

__global__ __launch_bounds__(256) void k_hist(const int* __restrict__ dst,
                                              unsigned short* __restrict__ partial,
                                              unsigned* __restrict__ gstart,
                                              unsigned* __restrict__ gend) {
    __shared__ int histo[RSPAN];
    const int r  = blockIdx.x & 15;
    const int c  = blockIdx.x >> 4;
    const int lo = r * RSPAN;
    for (int i = threadIdx.x; i < RSPAN; i += 256) histo[i] = 0;
    if (blockIdx.x == 0) {
        for (int i = threadIdx.x; i < N_GRAPHS; i += 256) { gstart[i] = 0u; gend[i] = 0u; }
    }
    __syncthreads();
    const int e0 = c * ESPAN;
    for (int e = e0 + threadIdx.x; e < e0 + ESPAN; e += 256) {
        int d = dst[e] - lo;
        if ((unsigned)d < (unsigned)RSPAN) atomicAdd(&histo[d], 1);
    }
    __syncthreads();
    unsigned short* p = partial + (size_t)(c * NRANGE + r) * RSPAN;
    for (int i = threadIdx.x; i < RSPAN; i += 256) p[i] = (unsigned short)histo[i];
}

__global__ __launch_bounds__(256) void k_colsum(unsigned short* __restrict__ partial,
                                                const int* __restrict__ batch,
                                                int* __restrict__ cnt,
                                                float* __restrict__ dinv,
                                                unsigned* __restrict__ gstart,
                                                unsigned* __restrict__ gend) {
    int i = blockIdx.x * 256 + threadIdx.x;
    if (i >= N_NODES) return;
    int r  = i / RSPAN;
    int li = i - r * RSPAN;
    int sum = 0;
#pragma unroll 4
    for (int c = 0; c < NCHUNK; ++c) {
        unsigned short* p = partial + (size_t)(c * NRANGE + r) * RSPAN + li;
        int v = *p;
        *p = (unsigned short)sum;     // exclusive prefix over chunks (fits u16)
        sum += v;
    }
    cnt[i]  = sum;
    dinv[i] = rsqrtf((float)(sum + 1));   // +1 self-loop
    int b = batch[i];
    if (i == 0) gstart[b] = 0u;
    else {
        int pb = batch[i - 1];
        if (b != pb) { gstart[b] = (unsigned)i; gend[pb] = (unsigned)i; }
    }
    if (i == N_NODES - 1) gend[b] = (unsigned)N_NODES;
}

__global__ __launch_bounds__(256) void k_bsum(const int* __restrict__ cnt,
                                              int* __restrict__ bsum) {
    __shared__ int ws[4];
    int i = blockIdx.x * 256 + threadIdx.x;
    int v = (i < N_NODES) ? cnt[i] : 0;
#pragma unroll
    for (int o = 32; o > 0; o >>= 1) v += __shfl_down(v, o, 64);
    if ((threadIdx.x & 63) == 0) ws[threadIdx.x >> 6] = v;
    __syncthreads();
    if (threadIdx.x == 0) bsum[blockIdx.x] = ws[0] + ws[1] + ws[2] + ws[3];
}

__global__ void k_scan_bsum(const int* __restrict__ bsum, int* __restrict__ boff) {
    __shared__ int s[256];
    int t = threadIdx.x;
    int v = (t < NB) ? bsum[t] : 0;
    s[t] = v;
    __syncthreads();
    for (int o = 1; o < 256; o <<= 1) {
        int u = (t >= o) ? s[t - o] : 0;
        __syncthreads();
        s[t] += u;
        __syncthreads();
    }
    if (t < NB) boff[t] = s[t] - v;
}

__global__ __launch_bounds__(256) void k_rowptr(const int* __restrict__ cnt,
                                                const int* __restrict__ boff,
                                                int* __restrict__ row_ptr) {
    __shared__ int s[256];
    int t = threadIdx.x;
    int i = blockIdx.x * 256 + t;
    int v = (i < N_NODES) ? cnt[i] : 0;
    s[t] = v;
    __syncthreads();
    for (int o = 1; o < 256; o <<= 1) {
        int u = (t >= o) ? s[t - o] : 0;
        __syncthreads();
        s[t] += u;
        __syncthreads();
    }
    int excl = boff[blockIdx.x] + s[t] - v;
    if (i < N_NODES)       row_ptr[i] = excl;
    else if (i == N_NODES) row_ptr[N_NODES] = excl;
}

__global__ __launch_bounds__(256) void k_fill2(const int* __restrict__ src,
                                               const int* __restrict__ dst,
                                               const unsigned short* __restrict__ partial,
                                               const int* __restrict__ row_ptr,
                                               const float* __restrict__ dinv,
                                               int* __restrict__ col,
                                               float* __restrict__ wnorm) {
    __shared__ int   lcur[RSPAN];
    __shared__ float dl[RSPAN];
    const int r  = blockIdx.x & 15;
    const int c  = blockIdx.x >> 4;
    const int lo = r * RSPAN;
    const unsigned short* pp = partial + (size_t)(c * NRANGE + r) * RSPAN;
    for (int i = threadIdx.x; i < RSPAN; i += 256) {
        lcur[i] = row_ptr[lo + i] + (int)pp[i];
        dl[i]   = dinv[lo + i];
    }
    __syncthreads();
    const int e0 = c * ESPAN;
    for (int e = e0 + threadIdx.x; e < e0 + ESPAN; e += 256) {
        int d = dst[e] - lo;
        int s = src[e];
        if ((unsigned)d < (unsigned)RSPAN) {
            int pos = atomicAdd(&lcur[d], 1);
            col[pos]   = s;
            wnorm[pos] = dinv[s] * dl[d];
        }
    }
}

// x (f32) -> xb (bf16), vectorized grid-stride
__global__ __launch_bounds__(256) void k_cvt(const float* __restrict__ x,
                                             unsigned short* __restrict__ xb) {
    const int total = N_NODES * 32;    // float4 groups
    for (int t = blockIdx.x * 256 + threadIdx.x; t < total; t += gridDim.x * 256) {
        float4 v = ((const float4*)x)[t];
        ushort4 o;
        o.x = f2b(v.x); o.y = f2b(v.y); o.z = f2b(v.z); o.w = f2b(v.w);
        ((ushort4*)xb)[t] = o;
    }
}

// W[5][128][128] f32 -> fragment-ordered bf16 (RNE) for mfma_f32_16x16x32_bf16.
// Element index within layer: ((ntile*4 + kstep)*64 + lane)*8 + j, value =
// W[k][n] with k = kstep*32 + (lane>>4)*8 + j, n = ntile*16 + (lane&15).
__global__ __launch_bounds__(256) void k_prepw(const float* __restrict__ W,
                                               unsigned short* __restrict__ wh) {
    int t = blockIdx.x * 256 + threadIdx.x;          // (l, nt, ks, lane)
    if (t >= N_LAYERS * 8 * 4 * 64) return;
    int lane = t & 63;
    int ks   = (t >> 6) & 3;
    int nt   = (t >> 8) & 7;
    int l    = t >> 11;
    int n  = nt * 16 + (lane & 15);
    int kb = ks * 32 + (lane >> 4) * 8;
    size_t obase = (size_t)t * 8;
#pragma unroll
    for (int j = 0; j < 8; ++j) {
        float f = W[(size_t)l * 16384 + (kb + j) * DIM + n];
        wh[obase + j] = f2b(f);
    }
}

// ---------------------------------------------------------------- transform (MFMA)
// t(bf16) = hin(bf16) @ W_hi. hin is exactly bf16 -> single MFMA per 16x16
// tile, fp32 accumulate, bf16 store. 64 rows/block, 4 waves x 16 rows,
// W_hi fragment-ordered in 32KB LDS.
// Layouts (guide §3): A row=lane&15, k=(lane>>4)*8+j; B col=lane&15, same k;
// C/D col=lane&15, row=(lane>>4)*4+reg.
__global__ __launch_bounds__(256, 2) void k_gemm_mfma_b(const unsigned short* __restrict__ hin,
                                                        const unsigned short* __restrict__ wh,
                                                        unsigned short* __restrict__ t) {
    __shared__ short Whl[16384];   // 32KB, fragment-ordered W_hi

    const int tid  = threadIdx.x;
    const int wv   = tid >> 6;
    const int lane = tid & 63;
    const int rb   = blockIdx.x * 64;

    // stage fragment-ordered W_hi (2048 float4, coalesced, 8/thread)
    {
        const float4* GH = (const float4*)wh;
        float4* SH = (float4*)Whl;
#pragma unroll
        for (int i = 0; i < 8; ++i) SH[tid + i * 256] = GH[tid + i * 256];
    }

    // A loads (bf16, 16B per kstep): row = rb + wv*16 + (lane&15)
    int rowA = rb + wv * 16 + (lane & 15);
    if (rowA > N_NODES - 1) rowA = N_NODES - 1;     // clamp loads; store guarded
    const unsigned short* Ab = hin + (size_t)rowA * DIM + (lane >> 4) * 8;
    short8 a[4];
#pragma unroll
    for (int ks = 0; ks < 4; ++ks)
        a[ks] = *(const short8*)(Ab + ks * 32);

    __syncthreads();   // W staged

    f32x4 acc[8] = {};
    const short8* WH = (const short8*)Whl;
#pragma unroll
    for (int nt = 0; nt < 8; ++nt) {
#pragma unroll
        for (int ks = 0; ks < 4; ++ks) {
            short8 bh = WH[(nt * 4 + ks) * 64 + lane];
            acc[nt] = __builtin_amdgcn_mfma_f32_16x16x32_bf16(a[ks], bh, acc[nt], 0, 0, 0);
        }
    }

    // epilogue: C col = lane&15, row = (lane>>4)*4 + r ; store bf16, no bias
    const int rowC = rb + wv * 16 + (lane >> 4) * 4;
    const int cl   = lane & 15;
#pragma unroll
    for (int nt = 0; nt < 8; ++nt) {
#pragma unroll
        for (int r = 0; r < 4; ++r) {
            int row = rowC + r;
            if (row < N_NODES)
                t[(size_t)row * DIM + nt * 16 + cl] = f2b(acc[nt][r]);
        }
    }
}

// ---------------------------------------------------------------- aggregation
// hout(bf16) = relu( gather(t, bf16) + bias ). fp32 accumulate; fused
// bias+relu+bf16 epilogue. Half-wave per node, 8-deep unrolled gather.
__global__ __launch_bounds__(256) void k_agg_t(const unsigned short* __restrict__ t,
                                               const float* __restrict__ bias,
                                               unsigned short* __restrict__ hout,
                                               const float* __restrict__ dinv,
                                               const int* __restrict__ row_ptr,
                                               const int* __restrict__ col,
                                               const float* __restrict__ wnorm) {
    const int wid  = blockIdx.x * 4 + (threadIdx.x >> 6);
    const int half = (threadIdx.x >> 5) & 1;
    const int node = wid * 2 + half;            // 6250*4*2 = 50000 exactly
    const int slot = threadIdx.x & 31;
    const ushort4* __restrict__ t4 = (const ushort4*)t + slot;

    float di = dinv[node];
    float4 v = b2f4(t4[(size_t)node * 32]);
    float4 acc;
    acc.x = v.x * di * di; acc.y = v.y * di * di;   // self-loop
    acc.z = v.z * di * di; acc.w = v.w * di * di;

    int e0 = row_ptr[node], e1 = row_ptr[node + 1];
    const int last = e1 - 1;
    for (int e = e0; e < e1; e += 8) {
        int jj[8]; float wt[8];
#pragma unroll
        for (int i = 0; i < 8; ++i) {
            int ee = e + i;
            int cl = (ee <= last) ? ee : last;
            jj[i] = col[cl];
            wt[i] = (ee <= last) ? wnorm[cl] : 0.f;
        }
        ushort4 u[8];
#pragma unroll
        for (int i = 0; i < 8; ++i) u[i] = t4[(size_t)jj[i] * 32];
#pragma unroll
        for (int i = 0; i < 8; ++i) {
            float4 f = b2f4(u[i]);
            acc.x += f.x * wt[i]; acc.y += f.y * wt[i];
            acc.z += f.z * wt[i]; acc.w += f.w * wt[i];
        }
    }

    float4 bv = ((const float4*)bias)[slot];
    ushort4 o;
    o.x = f2b(fmaxf(acc.x + bv.x, 0.f));
    o.y = f2b(fmaxf(acc.y + bv.y, 0.f));
    o.z = f2b(fmaxf(acc.z + bv.z, 0.f));
    o.w = f2b(fmaxf(acc.w + bv.w, 0.f));
    ((ushort4*)hout)[(size_t)node * 32 + slot] = o;
}

// ---------------------------------------------------------------- pooling (bf16 in)
__global__ __launch_bounds__(512) void k_pool_b(const unsigned short* __restrict__ h,
                                                const unsigned* __restrict__ gstart,
                                                const unsigned* __restrict__ gend,
                                                float* __restrict__ out, int layer) {
    __shared__ float4 red[16][32];
    int g    = blockIdx.x;
    int slot = threadIdx.x & 31;
    int way  = threadIdx.x >> 5;
    unsigned s = gstart[g], e = gend[g];
    float4 sum = make_float4(0.f, 0.f, 0.f, 0.f);
    for (unsigned i = s + way; i < e; i += 16) {
        float4 v = b2f4(((const ushort4*)h)[(size_t)i * 32 + slot]);
        sum.x += v.x; sum.y += v.y; sum.z += v.z; sum.w += v.w;
    }
    red[way][slot] = sum;
    __syncthreads();
    if (threadIdx.x < 32) {
        float4 t = red[0][slot];
#pragma unroll
        for (int wy = 1; wy < 16; ++wy) {
            float4 v = red[wy][slot];
            t.x += v.x; t.y += v.y; t.z += v.z; t.w += v.w;
        }
        *(float4*)&out[(size_t)g * (N_LAYERS * DIM) + layer * DIM + slot * 4] = t;
    }
}

// ---------------------------------------------------------------- launch

extern "C" void kernel_launch(void* const* d_in, const int* in_sizes, int n_in,
                              void* d_out, int out_size, void* d_ws, size_t ws_size,
                              hipStream_t stream) {
    const float* x    = (const float*)d_in[0];
    const int*   ei   = (const int*)d_in[1];
    const int*   bat  = (const int*)d_in[2];
    const float* Ws   = (const float*)d_in[3];
    const float* bs   = (const float*)d_in[4];
    float*       outp = (float*)d_out;

    const int* srcp = ei;
    const int* dstp = ei + N_EDGES;

    char* base = (char*)d_ws;
    size_t off = 0;
    unsigned short* xb      = (unsigned short*)(base + off); off += (size_t)N_NODES * DIM * 2;
    unsigned short* tB      = (unsigned short*)(base + off); off += (size_t)N_NODES * DIM * 2;
    unsigned short* hB0     = (unsigned short*)(base + off); off += (size_t)N_NODES * DIM * 2;
    unsigned short* hB1     = (unsigned short*)(base + off); off += (size_t)N_NODES * DIM * 2;
    float*          dinv    = (float*)(base + off);          off += (size_t)N_NODES * 4;
    int*            cnt     = (int*)(base + off);            off += (size_t)N_NODES * 4;
    int*            row_ptr = (int*)(base + off);            off += 200016;
    int*            col     = (int*)(base + off);            off += (size_t)N_EDGES * 4;
    float*          wnorm   = (float*)(base + off);          off += (size_t)N_EDGES * 4;
    unsigned short* partial = (unsigned short*)(base + off); off += (size_t)NCHUNK * NRANGE * RSPAN * 2;  // 6.4MB
    unsigned short* wfh     = (unsigned short*)(base + off); off += (size_t)N_LAYERS * 16384 * 2;
    int*            bsum    = (int*)(base + off);            off += 1024;
    int*            boff    = (int*)(base + off);            off += 1024;
    unsigned*       gstart  = (unsigned*)(base + off);       off += 2048;
    unsigned*       gend    = (unsigned*)(base + off);       off += 2048;

    k_cvt<<<2048, 256, 0, stream>>>(x, xb);
    k_prepw<<<40, 256, 0, stream>>>(Ws, wfh);
    k_hist<<<NRANGE * NCHUNK, 256, 0, stream>>>(dstp, partial, gstart, gend);
    k_colsum<<<NB, 256, 0, stream>>>(partial, bat, cnt, dinv, gstart, gend);
    k_bsum<<<NB, 256, 0, stream>>>(cnt, bsum);
    k_scan_bsum<<<1, 256, 0, stream>>>(bsum, boff);
    k_rowptr<<<NB, 256, 0, stream>>>(cnt, boff, row_ptr);
    k_fill2<<<NRANGE * NCHUNK, 256, 0, stream>>>(srcp, dstp, partial, row_ptr, dinv,
                                                 col, wnorm);

    const int BAGG  = 6250;                      // 6250 * 4 waves * 2 nodes = 50000
    const int BGEMM = (N_NODES + 63) / 64;       // 782

    const unsigned short* hin = xb;
    unsigned short* houts[N_LAYERS] = { hB0, hB1, hB0, hB1, hB0 };
    for (int l = 0; l < N_LAYERS; ++l) {
        unsigned short* ho = houts[l];
        k_gemm_mfma_b<<<BGEMM, 256, 0, stream>>>(hin, wfh + (size_t)l * 16384, tB);
        k_agg_t<<<BAGG, 256, 0, stream>>>(tB, bs + (size_t)l * DIM, ho,
                                          dinv, row_ptr, col, wnorm);
        k_pool_b<<<N_GRAPHS, 512, 0, stream>>>(ho, gstart, gend, outp, l);
        hin = ho;
    }
}

// Round 13
// 272.554 us; speedup vs baseline: 1.8686x; 1.0227x over previous
//
#include <hip/hip_runtime.h>

#define N_NODES  50000
#define N_EDGES  600000
#define DIM      128
#define N_LAYERS 5
#define N_GRAPHS 512
#define NB       ((N_NODES + 255) / 256)   // 196
#define NRANGE   16
#define RSPAN    3125                      // 16 * 3125 = 50000
#define NCHUNK   128
#define ESPAN    4688                      // 128 * 4688 >= 600000 (guarded)
#define BGEMM    782                       // 64-row MFMA tiles

typedef __attribute__((ext_vector_type(8))) short short8;
typedef __attribute__((ext_vector_type(4))) float f32x4;

// bf16 <-> f32 bit helpers (RNE)
__device__ __forceinline__ unsigned short f2b(float f) {
    unsigned u = __float_as_uint(f);
    return (unsigned short)((u + 0x7FFFu + ((u >> 16) & 1u)) >> 16);
}
__device__ __forceinline__ float4 b2f4(ushort4 u) {
    float4 c;
    c.x = __uint_as_float((unsigned)u.x << 16);
    c.y = __uint_as_float((unsigned)u.y << 16);
    c.z = __uint_as_float((unsigned)u.z << 16);
    c.w = __uint_as_float((unsigned)u.w << 16);
    return c;
}

// ---------------------------------------------------------------- preprocess

// fused: blocks 0..39 build fragment-ordered bf16 W; blocks 40.. convert x->bf16
__global__ __launch_bounds__(256) void k_prep(const float* __restrict__ x,
                                              const float* __restrict__ W,
                                              unsigned short* __restrict__ xb,
                                              unsigned short* __restrict__ wh) {
    if (blockIdx.x < 40) {
        // W[5][128][128] f32 -> fragment order: ((nt*4+ks)*64+lane)*8+j,
        // k = ks*32 + (lane>>4)*8 + j, n = nt*16 + (lane&15)
        int t = blockIdx.x * 256 + threadIdx.x;      // < 10240 exactly
        int lane = t & 63;
        int ks   = (t >> 6) & 3;
        int nt   = (t >> 8) & 7;
        int l    = t >> 11;
        int n  = nt * 16 + (lane & 15);
        int kb = ks * 32 + (lane >> 4) * 8;
        size_t obase = (size_t)t * 8;
#pragma unroll
        for (int j = 0; j < 8; ++j) {
            float f = W[(size_t)l * 16384 + (kb + j) * DIM + n];
            wh[obase + j] = f2b(f);
        }
    } else {
        const int total = N_NODES * 32;              // float4 groups
        for (int t = (blockIdx.x - 40) * 256 + threadIdx.x; t < total; t += 1024 * 256) {
            float4 v = ((const float4*)x)[t];
            ushort4 o;
            o.x = f2b(v.x); o.y = f2b(v.y); o.z = f2b(v.z); o.w = f2b(v.w);
            ((ushort4*)xb)[t] = o;
        }
    }
}

// CSR build with ZERO global atomics: 16 node-ranges x 128 edge-chunks.
__global__ __launch_bounds__(256) void k_hist(const int* __restrict__ dst,
                                              unsigned short* __restrict__ partial,
                                              unsigned* __restrict__ gstart,
                                              unsigned* __restrict__ gend) {
    __shared__ int histo[RSPAN];
    const int r  = blockIdx.x & 15;
    const int c  = blockIdx.x >> 4;
    const int lo = r * RSPAN;
    for (int i = threadIdx.x; i < RSPAN; i += 256) histo[i] = 0;
    if (blockIdx.x == 0) {
        for (int i = threadIdx.x; i < N_GRAPHS; i += 256) { gstart[i] = 0u; gend[i] = 0u; }
    }
    __syncthreads();
    const int e0 = c * ESPAN;
    int e1 = e0 + ESPAN; if (e1 > N_EDGES) e1 = N_EDGES;
    for (int e = e0 + threadIdx.x; e < e1; e += 256) {
        int d = dst[e] - lo;
        if ((unsigned)d < (unsigned)RSPAN) atomicAdd(&histo[d], 1);
    }
    __syncthreads();
    unsigned short* p = partial + (size_t)(c * NRANGE + r) * RSPAN;
    for (int i = threadIdx.x; i < RSPAN; i += 256) p[i] = (unsigned short)histo[i];
}

// per node: cnt = sum over chunks (in-place exclusive chunk-prefix), dinv,
// graph ranges (sorted-batch boundaries), and FUSED per-block sum -> bsum.
__global__ __launch_bounds__(256) void k_colsum(unsigned short* __restrict__ partial,
                                                const int* __restrict__ batch,
                                                int* __restrict__ cnt,
                                                float* __restrict__ dinv,
                                                unsigned* __restrict__ gstart,
                                                unsigned* __restrict__ gend,
                                                int* __restrict__ bsum) {
    __shared__ int ws[4];
    int i = blockIdx.x * 256 + threadIdx.x;
    const int inb = (i < N_NODES);
    int sum = 0;
    if (inb) {
        int r  = i / RSPAN;
        int li = i - r * RSPAN;
#pragma unroll 4
        for (int c = 0; c < NCHUNK; ++c) {
            unsigned short* p = partial + (size_t)(c * NRANGE + r) * RSPAN + li;
            int v = *p;
            *p = (unsigned short)sum;     // exclusive prefix over chunks (fits u16)
            sum += v;
        }
    }
    // block sum -> bsum[blockIdx]
    int v = sum;
#pragma unroll
    for (int o = 32; o > 0; o >>= 1) v += __shfl_down(v, o, 64);
    if ((threadIdx.x & 63) == 0) ws[threadIdx.x >> 6] = v;
    __syncthreads();
    if (threadIdx.x == 0) bsum[blockIdx.x] = ws[0] + ws[1] + ws[2] + ws[3];

    if (inb) {
        cnt[i]  = sum;
        dinv[i] = rsqrtf((float)(sum + 1));   // +1 self-loop
        int b = batch[i];
        if (i == 0) gstart[b] = 0u;
        else {
            int pb = batch[i - 1];
            if (b != pb) { gstart[b] = (unsigned)i; gend[pb] = (unsigned)i; }
        }
        if (i == N_NODES - 1) gend[b] = (unsigned)N_NODES;
    }
}

__global__ void k_scan_bsum(const int* __restrict__ bsum, int* __restrict__ boff) {
    __shared__ int s[256];
    int t = threadIdx.x;
    int v = (t < NB) ? bsum[t] : 0;
    s[t] = v;
    __syncthreads();
    for (int o = 1; o < 256; o <<= 1) {
        int u = (t >= o) ? s[t - o] : 0;
        __syncthreads();
        s[t] += u;
        __syncthreads();
    }
    if (t < NB) boff[t] = s[t] - v;
}

__global__ __launch_bounds__(256) void k_rowptr(const int* __restrict__ cnt,
                                                const int* __restrict__ boff,
                                                int* __restrict__ row_ptr) {
    __shared__ int s[256];
    int t = threadIdx.x;
    int i = blockIdx.x * 256 + t;
    int v = (i < N_NODES) ? cnt[i] : 0;
    s[t] = v;
    __syncthreads();
    for (int o = 1; o < 256; o <<= 1) {
        int u = (t >= o) ? s[t - o] : 0;
        __syncthreads();
        s[t] += u;
        __syncthreads();
    }
    int excl = boff[blockIdx.x] + s[t] - v;
    if (i < N_NODES)       row_ptr[i] = excl;
    else if (i == N_NODES) row_ptr[N_NODES] = excl;
}

// CSR fill, LDS-cursor only (seeded row_ptr + chunk prefix -> no global atomics)
__global__ __launch_bounds__(256) void k_fill2(const int* __restrict__ src,
                                               const int* __restrict__ dst,
                                               const unsigned short* __restrict__ partial,
                                               const int* __restrict__ row_ptr,
                                               const float* __restrict__ dinv,
                                               int* __restrict__ col,
                                               float* __restrict__ wnorm) {
    __shared__ int   lcur[RSPAN];
    __shared__ float dl[RSPAN];
    const int r  = blockIdx.x & 15;
    const int c  = blockIdx.x >> 4;
    const int lo = r * RSPAN;
    const unsigned short* pp = partial + (size_t)(c * NRANGE + r) * RSPAN;
    for (int i = threadIdx.x; i < RSPAN; i += 256) {
        lcur[i] = row_ptr[lo + i] + (int)pp[i];
        dl[i]   = dinv[lo + i];
    }
    __syncthreads();
    const int e0 = c * ESPAN;
    int e1 = e0 + ESPAN; if (e1 > N_EDGES) e1 = N_EDGES;
    for (int e = e0 + threadIdx.x; e < e1; e += 256) {
        int d = dst[e] - lo;
        int s = src[e];
        if ((unsigned)d < (unsigned)RSPAN) {
            int pos = atomicAdd(&lcur[d], 1);
            col[pos]   = s;
            wnorm[pos] = dinv[s] * dl[d];
        }
    }
}

// ---------------------------------------------------------------- transform (MFMA) + hidden pool
// Blocks < BGEMM: t(bf16) = hin(bf16) @ W_hi (1 MFMA/tile, fp32 acc).
// Blocks >= BGEMM (when poolLayer >= 0): global-add-pool of hin (== hout of
// the previous layer, final at dispatch time) into out row poolLayer.
// Pool runs on CUs the GEMM leaves idle -> off the critical path.
__global__ __launch_bounds__(256, 2) void k_gemm_pool(const unsigned short* __restrict__ hin,
                                                      const unsigned short* __restrict__ wh,
                                                      unsigned short* __restrict__ t,
                                                      const unsigned* __restrict__ gstart,
                                                      const unsigned* __restrict__ gend,
                                                      float* __restrict__ out,
                                                      int poolLayer) {
    __shared__ char smem[32768];

    const int tid = threadIdx.x;

    if (blockIdx.x < BGEMM) {
        short* Whl = (short*)smem;     // fragment-ordered W_hi, 32KB
        const int wv   = tid >> 6;
        const int lane = tid & 63;
        const int rb   = blockIdx.x * 64;

        {   // stage W_hi (2048 float4, coalesced, 8/thread)
            const float4* GH = (const float4*)wh;
            float4* SH = (float4*)Whl;
#pragma unroll
            for (int i = 0; i < 8; ++i) SH[tid + i * 256] = GH[tid + i * 256];
        }

        // A loads (bf16): row = rb + wv*16 + (lane&15), k-base (lane>>4)*8
        int rowA = rb + wv * 16 + (lane & 15);
        if (rowA > N_NODES - 1) rowA = N_NODES - 1;   // clamp loads; store guarded
        const unsigned short* Ab = hin + (size_t)rowA * DIM + (lane >> 4) * 8;
        short8 a[4];
#pragma unroll
        for (int ks = 0; ks < 4; ++ks)
            a[ks] = *(const short8*)(Ab + ks * 32);

        __syncthreads();   // W staged

        f32x4 acc[8] = {};
        const short8* WH = (const short8*)Whl;
#pragma unroll
        for (int nt = 0; nt < 8; ++nt) {
#pragma unroll
            for (int ks = 0; ks < 4; ++ks) {
                short8 bh = WH[(nt * 4 + ks) * 64 + lane];
                acc[nt] = __builtin_amdgcn_mfma_f32_16x16x32_bf16(a[ks], bh, acc[nt], 0, 0, 0);
            }
        }

        // epilogue: C col = lane&15, row = (lane>>4)*4 + r; bf16 store
        const int rowC = rb + wv * 16 + (lane >> 4) * 4;
        const int cl   = lane & 15;
#pragma unroll
        for (int nt = 0; nt < 8; ++nt) {
#pragma unroll
            for (int r = 0; r < 4; ++r) {
                int row = rowC + r;
                if (row < N_NODES)
                    t[(size_t)row * DIM + nt * 16 + cl] = f2b(acc[nt][r]);
            }
        }
    } else {
        // pool of previous layer over hin; 256 threads, 8-way row split
        float4* red = (float4*)smem;   // [8][32]
        const int g    = blockIdx.x - BGEMM;
        const int slot = tid & 31;
        const int way  = tid >> 5;
        unsigned s = gstart[g], e = gend[g];
        float4 sum = make_float4(0.f, 0.f, 0.f, 0.f);
        for (unsigned i = s + way; i < e; i += 8) {
            float4 v = b2f4(((const ushort4*)hin)[(size_t)i * 32 + slot]);
            sum.x += v.x; sum.y += v.y; sum.z += v.z; sum.w += v.w;
        }
        red[way * 32 + slot] = sum;
        __syncthreads();
        if (tid < 32) {
            float4 tt = red[slot];
#pragma unroll
            for (int wy = 1; wy < 8; ++wy) {
                float4 v = red[wy * 32 + slot];
                tt.x += v.x; tt.y += v.y; tt.z += v.z; tt.w += v.w;
            }
            *(float4*)&out[(size_t)g * (N_LAYERS * DIM) + poolLayer * DIM + slot * 4] = tt;
        }
    }
}

// ---------------------------------------------------------------- aggregation
// hout(bf16) = relu( gather(t, bf16) + bias ). fp32 accumulate; fused
// bias+relu+bf16 epilogue. Half-wave per node, 8-deep unrolled gather.
__global__ __launch_bounds__(256) void k_agg_t(const unsigned short* __restrict__ t,
                                               const float* __restrict__ bias,
                                               unsigned short* __restrict__ hout,
                                               const float* __restrict__ dinv,
                                               const int* __restrict__ row_ptr,
                                               const int* __restrict__ col,
                                               const float* __restrict__ wnorm) {
    const int wid  = blockIdx.x * 4 + (threadIdx.x >> 6);
    const int half = (threadIdx.x >> 5) & 1;
    const int node = wid * 2 + half;            // 6250*4*2 = 50000 exactly
    const int slot = threadIdx.x & 31;
    const ushort4* __restrict__ t4 = (const ushort4*)t + slot;

    float di = dinv[node];
    float4 v = b2f4(t4[(size_t)node * 32]);
    float4 acc;
    acc.x = v.x * di * di; acc.y = v.y * di * di;   // self-loop
    acc.z = v.z * di * di; acc.w = v.w * di * di;

    int e0 = row_ptr[node], e1 = row_ptr[node + 1];
    const int last = e1 - 1;
    for (int e = e0; e < e1; e += 8) {
        int jj[8]; float wt[8];
#pragma unroll
        for (int i = 0; i < 8; ++i) {
            int ee = e + i;
            int cl = (ee <= last) ? ee : last;
            jj[i] = col[cl];
            wt[i] = (ee <= last) ? wnorm[cl] : 0.f;
        }
        ushort4 u[8];
#pragma unroll
        for (int i = 0; i < 8; ++i) u[i] = t4[(size_t)jj[i] * 32];
#pragma unroll
        for (int i = 0; i < 8; ++i) {
            float4 f = b2f4(u[i]);
            acc.x += f.x * wt[i]; acc.y += f.y * wt[i];
            acc.z += f.z * wt[i]; acc.w += f.w * wt[i];
        }
    }

    float4 bv = ((const float4*)bias)[slot];
    ushort4 o;
    o.x = f2b(fmaxf(acc.x + bv.x, 0.f));
    o.y = f2b(fmaxf(acc.y + bv.y, 0.f));
    o.z = f2b(fmaxf(acc.z + bv.z, 0.f));
    o.w = f2b(fmaxf(acc.w + bv.w, 0.f));
    ((ushort4*)hout)[(size_t)node * 32 + slot] = o;
}

// ---------------------------------------------------------------- standalone pool (last layer)
__global__ __launch_bounds__(512) void k_pool_b(const unsigned short* __restrict__ h,
                                                const unsigned* __restrict__ gstart,
                                                const unsigned* __restrict__ gend,
                                                float* __restrict__ out, int layer) {
    __shared__ float4 red[16][32];
    int g    = blockIdx.x;
    int slot = threadIdx.x & 31;
    int way  = threadIdx.x >> 5;
    unsigned s = gstart[g], e = gend[g];
    float4 sum = make_float4(0.f, 0.f, 0.f, 0.f);
    for (unsigned i = s + way; i < e; i += 16) {
        float4 v = b2f4(((const ushort4*)h)[(size_t)i * 32 + slot]);
        sum.x += v.x; sum.y += v.y; sum.z += v.z; sum.w += v.w;
    }
    red[way][slot] = sum;
    __syncthreads();
    if (threadIdx.x < 32) {
        float4 t = red[0][slot];
#pragma unroll
        for (int wy = 1; wy < 16; ++wy) {
            float4 v = red[wy][slot];
            t.x += v.x; t.y += v.y; t.z += v.z; t.w += v.w;
        }
        *(float4*)&out[(size_t)g * (N_LAYERS * DIM) + layer * DIM + slot * 4] = t;
    }
}

// ---------------------------------------------------------------- launch

extern "C" void kernel_launch(void* const* d_in, const int* in_sizes, int n_in,
                              void* d_out, int out_size, void* d_ws, size_t ws_size,
                              hipStream_t stream) {
    const float* x    = (const float*)d_in[0];
    const int*   ei   = (const int*)d_in[1];
    const int*   bat  = (const int*)d_in[2];
    const float* Ws   = (const float*)d_in[3];
    const float* bs   = (const float*)d_in[4];
    float*       outp = (float*)d_out;

    const int* srcp = ei;
    const int* dstp = ei + N_EDGES;

    char* base = (char*)d_ws;
    size_t off = 0;
    unsigned short* xb      = (unsigned short*)(base + off); off += (size_t)N_NODES * DIM * 2;
    unsigned short* tB      = (unsigned short*)(base + off); off += (size_t)N_NODES * DIM * 2;
    unsigned short* hB0     = (unsigned short*)(base + off); off += (size_t)N_NODES * DIM * 2;
    unsigned short* hB1     = (unsigned short*)(base + off); off += (size_t)N_NODES * DIM * 2;
    float*          dinv    = (float*)(base + off);          off += (size_t)N_NODES * 4;
    int*            cnt     = (int*)(base + off);            off += (size_t)N_NODES * 4;
    int*            row_ptr = (int*)(base + off);            off += 200016;
    int*            col     = (int*)(base + off);            off += (size_t)N_EDGES * 4;
    float*          wnorm   = (float*)(base + off);          off += (size_t)N_EDGES * 4;
    unsigned short* partial = (unsigned short*)(base + off); off += (size_t)NCHUNK * NRANGE * RSPAN * 2;  // 12.8MB
    unsigned short* wfh     = (unsigned short*)(base + off); off += (size_t)N_LAYERS * 16384 * 2;
    int*            bsum    = (int*)(base + off);            off += 1024;
    int*            boff    = (int*)(base + off);            off += 1024;
    unsigned*       gstart  = (unsigned*)(base + off);       off += 2048;
    unsigned*       gend    = (unsigned*)(base + off);       off += 2048;

    k_prep<<<1064, 256, 0, stream>>>(x, Ws, xb, wfh);
    k_hist<<<NRANGE * NCHUNK, 256, 0, stream>>>(dstp, partial, gstart, gend);
    k_colsum<<<NB, 256, 0, stream>>>(partial, bat, cnt, dinv, gstart, gend, bsum);
    k_scan_bsum<<<1, 256, 0, stream>>>(bsum, boff);
    k_rowptr<<<NB, 256, 0, stream>>>(cnt, boff, row_ptr);
    k_fill2<<<NRANGE * NCHUNK, 256, 0, stream>>>(srcp, dstp, partial, row_ptr, dinv,
                                                 col, wnorm);

    const int BAGG = 6250;                       // 6250 * 4 waves * 2 nodes = 50000

    const unsigned short* hin = xb;
    unsigned short* houts[N_LAYERS] = { hB0, hB1, hB0, hB1, hB0 };
    for (int l = 0; l < N_LAYERS; ++l) {
        unsigned short* ho = houts[l];
        int grid = (l == 0) ? BGEMM : BGEMM + N_GRAPHS;   // pool of layer l-1 rides along
        k_gemm_pool<<<grid, 256, 0, stream>>>(hin, wfh + (size_t)l * 16384, tB,
                                              gstart, gend, outp, l - 1);
        k_agg_t<<<BAGG, 256, 0, stream>>>(tB, bs + (size_t)l * DIM, ho,
                                          dinv, row_ptr, col, wnorm);
        hin = ho;
    }
    k_pool_b<<<N_GRAPHS, 512, 0, stream>>>(houts[4], gstart, gend, outp, 4);
}

// Round 14
// 258.404 us; speedup vs baseline: 1.9710x; 1.0548x over previous
//
#include <hip/hip_runtime.h>

#define N_NODES  50000
#define N_EDGES  600000
#define DIM      128
#define N_LAYERS 5
#define N_GRAPHS 512
#define NB       ((N_NODES + 255) / 256)   // 196
#define NRANGE   16
#define RSPAN    3125                      // 16 * 3125 = 50000
#define NCHUNK   64
#define ESPAN    9375                      // 64 * 9375 = 600000
#define NHB      (NRANGE * NCHUNK)         // 1024 hist/fill blocks
#define BGEMM    782                       // 64-row MFMA tiles

typedef __attribute__((ext_vector_type(8))) short short8;
typedef __attribute__((ext_vector_type(4))) float f32x4;

// bf16 <-> f32 bit helpers (RNE)
__device__ __forceinline__ unsigned short f2b(float f) {
    unsigned u = __float_as_uint(f);
    return (unsigned short)((u + 0x7FFFu + ((u >> 16) & 1u)) >> 16);
}
__device__ __forceinline__ float4 b2f4(ushort4 u) {
    float4 c;
    c.x = __uint_as_float((unsigned)u.x << 16);
    c.y = __uint_as_float((unsigned)u.y << 16);
    c.z = __uint_as_float((unsigned)u.z << 16);
    c.w = __uint_as_float((unsigned)u.w << 16);
    return c;
}

// ---------------------------------------------------------------- GEMM body (shared)
// t(bf16) = hin(bf16) @ W_hi, one 64-row tile. Whl = 32KB fragment-ordered LDS.
// Layouts (guide §3): A row=lane&15, k=(lane>>4)*8+j; B col=lane&15, same k;
// C/D col=lane&15, row=(lane>>4)*4+reg.
__device__ __forceinline__ void gemm_tile(const unsigned short* __restrict__ hin,
                                          const unsigned short* __restrict__ wh,
                                          unsigned short* __restrict__ t,
                                          short* Whl, int tile, int tid) {
    const int wv   = tid >> 6;
    const int lane = tid & 63;
    const int rb   = tile * 64;

    {   // stage W_hi (2048 float4, coalesced, 8/thread)
        const float4* GH = (const float4*)wh;
        float4* SH = (float4*)Whl;
#pragma unroll
        for (int i = 0; i < 8; ++i) SH[tid + i * 256] = GH[tid + i * 256];
    }

    int rowA = rb + wv * 16 + (lane & 15);
    if (rowA > N_NODES - 1) rowA = N_NODES - 1;   // clamp loads; store guarded
    const unsigned short* Ab = hin + (size_t)rowA * DIM + (lane >> 4) * 8;
    short8 a[4];
#pragma unroll
    for (int ks = 0; ks < 4; ++ks)
        a[ks] = *(const short8*)(Ab + ks * 32);

    __syncthreads();   // W staged

    f32x4 acc[8] = {};
    const short8* WH = (const short8*)Whl;
#pragma unroll
    for (int nt = 0; nt < 8; ++nt) {
#pragma unroll
        for (int ks = 0; ks < 4; ++ks) {
            short8 bh = WH[(nt * 4 + ks) * 64 + lane];
            acc[nt] = __builtin_amdgcn_mfma_f32_16x16x32_bf16(a[ks], bh, acc[nt], 0, 0, 0);
        }
    }

    const int rowC = rb + wv * 16 + (lane >> 4) * 4;
    const int cl   = lane & 15;
#pragma unroll
    for (int nt = 0; nt < 8; ++nt) {
#pragma unroll
        for (int r = 0; r < 4; ++r) {
            int row = rowC + r;
            if (row < N_NODES)
                t[(size_t)row * DIM + nt * 16 + cl] = f2b(acc[nt][r]);
        }
    }
}

// ---------------------------------------------------------------- preprocess
// Fused dispatch 1: blocks [0,NHB) LDS-histogram; [NHB,NHB+40) W->bf16 frag;
// [NHB+40, NHB+40+1024) x->bf16. All independent.
__global__ __launch_bounds__(256) void k_prep_hist(const float* __restrict__ x,
                                                   const float* __restrict__ W,
                                                   unsigned short* __restrict__ xb,
                                                   unsigned short* __restrict__ wh,
                                                   const int* __restrict__ dst,
                                                   unsigned short* __restrict__ partial,
                                                   unsigned* __restrict__ gstart,
                                                   unsigned* __restrict__ gend) {
    __shared__ int histo[RSPAN];
    if (blockIdx.x < NHB) {
        const int r  = blockIdx.x & 15;
        const int c  = blockIdx.x >> 4;
        const int lo = r * RSPAN;
        for (int i = threadIdx.x; i < RSPAN; i += 256) histo[i] = 0;
        if (blockIdx.x == 0) {
            for (int i = threadIdx.x; i < N_GRAPHS; i += 256) { gstart[i] = 0u; gend[i] = 0u; }
        }
        __syncthreads();
        const int e0 = c * ESPAN;
        for (int e = e0 + threadIdx.x; e < e0 + ESPAN; e += 256) {
            int d = dst[e] - lo;
            if ((unsigned)d < (unsigned)RSPAN) atomicAdd(&histo[d], 1);
        }
        __syncthreads();
        unsigned short* p = partial + (size_t)(c * NRANGE + r) * RSPAN;
        for (int i = threadIdx.x; i < RSPAN; i += 256) p[i] = (unsigned short)histo[i];
    } else if (blockIdx.x < NHB + 40) {
        // W[5][128][128] f32 -> fragment order: ((nt*4+ks)*64+lane)*8+j,
        // k = ks*32 + (lane>>4)*8 + j, n = nt*16 + (lane&15)
        int t = (blockIdx.x - NHB) * 256 + threadIdx.x;   // < 10240 exactly
        int lane = t & 63;
        int ks   = (t >> 6) & 3;
        int nt   = (t >> 8) & 7;
        int l    = t >> 11;
        int n  = nt * 16 + (lane & 15);
        int kb = ks * 32 + (lane >> 4) * 8;
        size_t obase = (size_t)t * 8;
#pragma unroll
        for (int j = 0; j < 8; ++j) {
            float f = W[(size_t)l * 16384 + (kb + j) * DIM + n];
            wh[obase + j] = f2b(f);
        }
    } else {
        const int total = N_NODES * 32;                   // float4 groups
        for (int t = (blockIdx.x - NHB - 40) * 256 + threadIdx.x; t < total;
             t += 1024 * 256) {
            float4 v = ((const float4*)x)[t];
            ushort4 o;
            o.x = f2b(v.x); o.y = f2b(v.y); o.z = f2b(v.z); o.w = f2b(v.w);
            ((ushort4*)xb)[t] = o;
        }
    }
}

// per node: cnt = sum over chunks (in-place exclusive chunk-prefix), dinv,
// graph ranges (sorted-batch boundaries), fused per-block sum -> bsum.
__global__ __launch_bounds__(256) void k_colsum(unsigned short* __restrict__ partial,
                                                const int* __restrict__ batch,
                                                int* __restrict__ cnt,
                                                float* __restrict__ dinv,
                                                unsigned* __restrict__ gstart,
                                                unsigned* __restrict__ gend,
                                                int* __restrict__ bsum) {
    __shared__ int ws[4];
    int i = blockIdx.x * 256 + threadIdx.x;
    const int inb = (i < N_NODES);
    int sum = 0;
    if (inb) {
        int r  = i / RSPAN;
        int li = i - r * RSPAN;
#pragma unroll 4
        for (int c = 0; c < NCHUNK; ++c) {
            unsigned short* p = partial + (size_t)(c * NRANGE + r) * RSPAN + li;
            int v = *p;
            *p = (unsigned short)sum;     // exclusive prefix over chunks (fits u16)
            sum += v;
        }
    }
    int v = sum;
#pragma unroll
    for (int o = 32; o > 0; o >>= 1) v += __shfl_down(v, o, 64);
    if ((threadIdx.x & 63) == 0) ws[threadIdx.x >> 6] = v;
    __syncthreads();
    if (threadIdx.x == 0) bsum[blockIdx.x] = ws[0] + ws[1] + ws[2] + ws[3];

    if (inb) {
        cnt[i]  = sum;
        dinv[i] = rsqrtf((float)(sum + 1));   // +1 self-loop
        int b = batch[i];
        if (i == 0) gstart[b] = 0u;
        else {
            int pb = batch[i - 1];
            if (b != pb) { gstart[b] = (unsigned)i; gend[pb] = (unsigned)i; }
        }
        if (i == N_NODES - 1) gend[b] = (unsigned)N_NODES;
    }
}

__global__ void k_scan_bsum(const int* __restrict__ bsum, int* __restrict__ boff) {
    __shared__ int s[256];
    int t = threadIdx.x;
    int v = (t < NB) ? bsum[t] : 0;
    s[t] = v;
    __syncthreads();
    for (int o = 1; o < 256; o <<= 1) {
        int u = (t >= o) ? s[t - o] : 0;
        __syncthreads();
        s[t] += u;
        __syncthreads();
    }
    if (t < NB) boff[t] = s[t] - v;
}

__global__ __launch_bounds__(256) void k_rowptr(const int* __restrict__ cnt,
                                                const int* __restrict__ boff,
                                                int* __restrict__ row_ptr) {
    __shared__ int s[256];
    int t = threadIdx.x;
    int i = blockIdx.x * 256 + t;
    int v = (i < N_NODES) ? cnt[i] : 0;
    s[t] = v;
    __syncthreads();
    for (int o = 1; o < 256; o <<= 1) {
        int u = (t >= o) ? s[t - o] : 0;
        __syncthreads();
        s[t] += u;
        __syncthreads();
    }
    int excl = boff[blockIdx.x] + s[t] - v;
    if (i < N_NODES)       row_ptr[i] = excl;
    else if (i == N_NODES) row_ptr[N_NODES] = excl;
}

// Fused dispatch 5: blocks [0,NHB) CSR fill (LDS cursor, no global atomics);
// blocks [NHB, NHB+BGEMM) layer-0 GEMM (independent of CSR -> hides under fill).
__global__ __launch_bounds__(256, 2) void k_fill_gemm(const int* __restrict__ src,
                                                      const int* __restrict__ dst,
                                                      const unsigned short* __restrict__ partial,
                                                      const int* __restrict__ row_ptr,
                                                      const float* __restrict__ dinv,
                                                      int* __restrict__ col,
                                                      float* __restrict__ wnorm,
                                                      const unsigned short* __restrict__ hin,
                                                      const unsigned short* __restrict__ wh,
                                                      unsigned short* __restrict__ t) {
    __shared__ char smem[32768];
    const int tid = threadIdx.x;
    if (blockIdx.x < NHB) {
        int*   lcur = (int*)smem;               // 12.5KB
        float* dl   = (float*)(smem + 12512);   // 12.5KB
        const int r  = blockIdx.x & 15;
        const int c  = blockIdx.x >> 4;
        const int lo = r * RSPAN;
        const unsigned short* pp = partial + (size_t)(c * NRANGE + r) * RSPAN;
        for (int i = tid; i < RSPAN; i += 256) {
            lcur[i] = row_ptr[lo + i] + (int)pp[i];
            dl[i]   = dinv[lo + i];
        }
        __syncthreads();
        const int e0 = c * ESPAN;
        for (int e = e0 + tid; e < e0 + ESPAN; e += 256) {
            int d = dst[e] - lo;
            int s = src[e];
            if ((unsigned)d < (unsigned)RSPAN) {
                int pos = atomicAdd(&lcur[d], 1);
                col[pos]   = s;
                wnorm[pos] = dinv[s] * dl[d];
            }
        }
    } else {
        gemm_tile(hin, wh, t, (short*)smem, blockIdx.x - NHB, tid);
    }
}

// ---------------------------------------------------------------- transform (MFMA) + hidden pool
// Blocks < BGEMM: GEMM of layer l. Blocks >= BGEMM: global-add-pool of hin
// (hout of layer l-1, final at dispatch time) into out row poolLayer.
__global__ __launch_bounds__(256, 2) void k_gemm_pool(const unsigned short* __restrict__ hin,
                                                      const unsigned short* __restrict__ wh,
                                                      unsigned short* __restrict__ t,
                                                      const unsigned* __restrict__ gstart,
                                                      const unsigned* __restrict__ gend,
                                                      float* __restrict__ out,
                                                      int poolLayer) {
    __shared__ char smem[32768];
    const int tid = threadIdx.x;
    if (blockIdx.x < BGEMM) {
        gemm_tile(hin, wh, t, (short*)smem, blockIdx.x, tid);
    } else {
        float4* red = (float4*)smem;   // [8][32]
        const int g    = blockIdx.x - BGEMM;
        const int slot = tid & 31;
        const int way  = tid >> 5;
        unsigned s = gstart[g], e = gend[g];
        float4 sum = make_float4(0.f, 0.f, 0.f, 0.f);
        for (unsigned i = s + way; i < e; i += 8) {
            float4 v = b2f4(((const ushort4*)hin)[(size_t)i * 32 + slot]);
            sum.x += v.x; sum.y += v.y; sum.z += v.z; sum.w += v.w;
        }
        red[way * 32 + slot] = sum;
        __syncthreads();
        if (tid < 32) {
            float4 tt = red[slot];
#pragma unroll
            for (int wy = 1; wy < 8; ++wy) {
                float4 v = red[wy * 32 + slot];
                tt.x += v.x; tt.y += v.y; tt.z += v.z; tt.w += v.w;
            }
            *(float4*)&out[(size_t)g * (N_LAYERS * DIM) + poolLayer * DIM + slot * 4] = tt;
        }
    }
}

// ---------------------------------------------------------------- aggregation
// hout(bf16) = relu( gather(t, bf16) + bias ). fp32 accumulate; fused
// bias+relu+bf16 epilogue. Half-wave per node, 8-deep unrolled gather.
__global__ __launch_bounds__(256) void k_agg_t(const unsigned short* __restrict__ t,
                                               const float* __restrict__ bias,
                                               unsigned short* __restrict__ hout,
                                               const float* __restrict__ dinv,
                                               const int* __restrict__ row_ptr,
                                               const int* __restrict__ col,
                                               const float* __restrict__ wnorm) {
    const int wid  = blockIdx.x * 4 + (threadIdx.x >> 6);
    const int half = (threadIdx.x >> 5) & 1;
    const int node = wid * 2 + half;            // 6250*4*2 = 50000 exactly
    const int slot = threadIdx.x & 31;
    const ushort4* __restrict__ t4 = (const ushort4*)t + slot;

    float di = dinv[node];
    float4 v = b2f4(t4[(size_t)node * 32]);
    float4 acc;
    acc.x = v.x * di * di; acc.y = v.y * di * di;   // self-loop
    acc.z = v.z * di * di; acc.w = v.w * di * di;

    int e0 = row_ptr[node], e1 = row_ptr[node + 1];
    const int last = e1 - 1;
    for (int e = e0; e < e1; e += 8) {
        int jj[8]; float wt[8];
#pragma unroll
        for (int i = 0; i < 8; ++i) {
            int ee = e + i;
            int cl = (ee <= last) ? ee : last;
            jj[i] = col[cl];
            wt[i] = (ee <= last) ? wnorm[cl] : 0.f;
        }
        ushort4 u[8];
#pragma unroll
        for (int i = 0; i < 8; ++i) u[i] = t4[(size_t)jj[i] * 32];
#pragma unroll
        for (int i = 0; i < 8; ++i) {
            float4 f = b2f4(u[i]);
            acc.x += f.x * wt[i]; acc.y += f.y * wt[i];
            acc.z += f.z * wt[i]; acc.w += f.w * wt[i];
        }
    }

    float4 bv = ((const float4*)bias)[slot];
    ushort4 o;
    o.x = f2b(fmaxf(acc.x + bv.x, 0.f));
    o.y = f2b(fmaxf(acc.y + bv.y, 0.f));
    o.z = f2b(fmaxf(acc.z + bv.z, 0.f));
    o.w = f2b(fmaxf(acc.w + bv.w, 0.f));
    ((ushort4*)hout)[(size_t)node * 32 + slot] = o;
}

// ---------------------------------------------------------------- standalone pool (last layer)
__global__ __launch_bounds__(512) void k_pool_b(const unsigned short* __restrict__ h,
                                                const unsigned* __restrict__ gstart,
                                                const unsigned* __restrict__ gend,
                                                float* __restrict__ out, int layer) {
    __shared__ float4 red[16][32];
    int g    = blockIdx.x;
    int slot = threadIdx.x & 31;
    int way  = threadIdx.x >> 5;
    unsigned s = gstart[g], e = gend[g];
    float4 sum = make_float4(0.f, 0.f, 0.f, 0.f);
    for (unsigned i = s + way; i < e; i += 16) {
        float4 v = b2f4(((const ushort4*)h)[(size_t)i * 32 + slot]);
        sum.x += v.x; sum.y += v.y; sum.z += v.z; sum.w += v.w;
    }
    red[way][slot] = sum;
    __syncthreads();
    if (threadIdx.x < 32) {
        float4 t = red[0][slot];
#pragma unroll
        for (int wy = 1; wy < 16; ++wy) {
            float4 v = red[wy][slot];
            t.x += v.x; t.y += v.y; t.z += v.z; t.w += v.w;
        }
        *(float4*)&out[(size_t)g * (N_LAYERS * DIM) + layer * DIM + slot * 4] = t;
    }
}

// ---------------------------------------------------------------- launch

extern "C" void kernel_launch(void* const* d_in, const int* in_sizes, int n_in,
                              void* d_out, int out_size, void* d_ws, size_t ws_size,
                              hipStream_t stream) {
    const float* x    = (const float*)d_in[0];
    const int*   ei   = (const int*)d_in[1];
    const int*   bat  = (const int*)d_in[2];
    const float* Ws   = (const float*)d_in[3];
    const float* bs   = (const float*)d_in[4];
    float*       outp = (float*)d_out;

    const int* srcp = ei;
    const int* dstp = ei + N_EDGES;

    char* base = (char*)d_ws;
    size_t off = 0;
    unsigned short* xb      = (unsigned short*)(base + off); off += (size_t)N_NODES * DIM * 2;
    unsigned short* tB      = (unsigned short*)(base + off); off += (size_t)N_NODES * DIM * 2;
    unsigned short* hB0     = (unsigned short*)(base + off); off += (size_t)N_NODES * DIM * 2;
    unsigned short* hB1     = (unsigned short*)(base + off); off += (size_t)N_NODES * DIM * 2;
    float*          dinv    = (float*)(base + off);          off += (size_t)N_NODES * 4;
    int*            cnt     = (int*)(base + off);            off += (size_t)N_NODES * 4;
    int*            row_ptr = (int*)(base + off);            off += 200016;
    int*            col     = (int*)(base + off);            off += (size_t)N_EDGES * 4;
    float*          wnorm   = (float*)(base + off);          off += (size_t)N_EDGES * 4;
    unsigned short* partial = (unsigned short*)(base + off); off += (size_t)NCHUNK * NRANGE * RSPAN * 2;  // 6.4MB
    unsigned short* wfh     = (unsigned short*)(base + off); off += (size_t)N_LAYERS * 16384 * 2;
    int*            bsum    = (int*)(base + off);            off += 1024;
    int*            boff    = (int*)(base + off);            off += 1024;
    unsigned*       gstart  = (unsigned*)(base + off);       off += 2048;
    unsigned*       gend    = (unsigned*)(base + off);       off += 2048;

    k_prep_hist<<<NHB + 40 + 1024, 256, 0, stream>>>(x, Ws, xb, wfh, dstp,
                                                     partial, gstart, gend);
    k_colsum<<<NB, 256, 0, stream>>>(partial, bat, cnt, dinv, gstart, gend, bsum);
    k_scan_bsum<<<1, 256, 0, stream>>>(bsum, boff);
    k_rowptr<<<NB, 256, 0, stream>>>(cnt, boff, row_ptr);
    // fill + layer-0 GEMM (independent of CSR) in one dispatch
    k_fill_gemm<<<NHB + BGEMM, 256, 0, stream>>>(srcp, dstp, partial, row_ptr, dinv,
                                                 col, wnorm, xb, wfh, tB);

    const int BAGG = 6250;                       // 6250 * 4 waves * 2 nodes = 50000

    unsigned short* houts[N_LAYERS] = { hB0, hB1, hB0, hB1, hB0 };
    k_agg_t<<<BAGG, 256, 0, stream>>>(tB, bs, hB0, dinv, row_ptr, col, wnorm);
    const unsigned short* hin = hB0;
    for (int l = 1; l < N_LAYERS; ++l) {
        unsigned short* ho = houts[l];
        k_gemm_pool<<<BGEMM + N_GRAPHS, 256, 0, stream>>>(hin, wfh + (size_t)l * 16384,
                                                          tB, gstart, gend, outp, l - 1);
        k_agg_t<<<BAGG, 256, 0, stream>>>(tB, bs + (size_t)l * DIM, ho,
                                          dinv, row_ptr, col, wnorm);
        hin = ho;
    }
    k_pool_b<<<N_GRAPHS, 512, 0, stream>>>(houts[4], gstart, gend, outp, 4);
}